// Round 14
// baseline (498.698 us; speedup 1.0000x reference)
//
#include <hip/hip_runtime.h>
#include <math.h>

#define D 256
#define T 4096
#define KT (17408/2)       // shorts per K tile (stride incl. pad)
#define VT (20480/2)       // shorts per V^T tile
#define PSTR ((size_t)4*T*D)  // shorts per bf16 partial buffer

typedef __attribute__((ext_vector_type(8))) short bf16x8;
typedef __attribute__((ext_vector_type(4))) float f32x4;
typedef __attribute__((ext_vector_type(8))) unsigned short u16x8;
typedef __attribute__((ext_vector_type(4))) unsigned int u32x4;

// log2(e)/16: folds softmax 1/sqrt(D) scale AND exp->exp2 conversion into q
#define QSCALE 0.0901684850f

__device__ __forceinline__ unsigned short f2bf(float x){
  unsigned int u = __float_as_uint(x);
  unsigned int r = (u + 0x7FFFu + ((u >> 16) & 1u)) >> 16;
  return (unsigned short)r;
}
__device__ __forceinline__ float bf2f(unsigned short h){
  return __uint_as_float(((unsigned int)h) << 16);
}
__device__ __forceinline__ unsigned int cvtpk(float lo, float hi){
  unsigned int w;
  asm("v_cvt_pk_bf16_f32 %0, %1, %2" : "=v"(w) : "v"(lo), "v"(hi));
  return w;
}

__device__ __forceinline__ void gl_lds16(const void* g, void* l){
  __builtin_amdgcn_global_load_lds((const __attribute__((address_space(1))) unsigned int*)g,
                                   (__attribute__((address_space(3))) unsigned int*)l, 16, 0, 0);
}

// ---------------- prep: gates (block 0) + Wq bf16 image (blocks 1..8) ----------------
__global__ __launch_bounds__(256) void prep_kernel(
    const float* __restrict__ q_vec, const float* __restrict__ k_vec,
    const float* __restrict__ v_vec, const float* __restrict__ Ws,
    const float* __restrict__ bs, const float* __restrict__ Wt,
    const float* __restrict__ bt, const float* __restrict__ Wq,
    float* __restrict__ gates, unsigned short* __restrict__ wq_g){
  int t = threadIdx.x;
  if(blockIdx.x == 0){
    __shared__ float vv[D];
    vv[t]         = 1.f/(1.f + __expf(-v_vec[t]));
    gates[t]      = 1.f/(1.f + __expf(-q_vec[t]));   // gq
    gates[D + t]  = 1.f/(1.f + __expf(-k_vec[t]));   // gk
    __syncthreads();
    const f32x4* wsr = (const f32x4*)(Ws + (size_t)t*D);
    const f32x4* wtr = (const f32x4*)(Wt + (size_t)t*D);
    const f32x4* vvv = (const f32x4*)vv;
    f32x4 a0 = {0,0,0,0}, a1 = {0,0,0,0}, c0 = {0,0,0,0}, c1 = {0,0,0,0};
    for(int i=0;i<64;i+=2){
      f32x4 v0 = vvv[i], v1 = vvv[i+1];
      a0 += wsr[i]*v0; a1 += wsr[i+1]*v1;
      c0 += wtr[i]*v0; c1 += wtr[i+1]*v1;
    }
    f32x4 as = a0 + a1, cs = c0 + c1;
    float s1 = bs[t] + as[0]+as[1]+as[2]+as[3];
    float s2 = bt[t] + cs[0]+cs[1]+cs[2]+cs[3];
    gates[2*D + t] = (1.f/(1.f + __expf(-s1))) * tanhf(s2);  // v_gate
  } else {
    int kc = blockIdx.x - 1;
    const float* src = Wq + (size_t)t*D + kc*32;
    unsigned short* dst = wq_g + (size_t)kc*10240 + t*40;
    #pragma unroll
    for(int u=0;u<4;u++){
      bf16x8 pk;
      #pragma unroll
      for(int x=0;x<8;x++) pk[x] = (short)f2bf(src[u*8+x]);
      *(bf16x8*)&dst[u*8] = pk;
    }
  }
}

// ---------------- mid: proj (blocks 0..255) + prep1 (blocks 256..767) ----------------
__global__ __launch_bounds__(256) void mid_kernel(
    const float* __restrict__ query, const unsigned short* __restrict__ wq_g,
    const float* __restrict__ bq, const float* __restrict__ gates,
    unsigned short* __restrict__ q_g,
    const float* __restrict__ value,
    unsigned short* __restrict__ k_g, unsigned short* __restrict__ vt_g){
  __shared__ __align__(16) unsigned short smem[2][10240];
  int tid = threadIdx.x;
  if(blockIdx.x < 256){
    // ---- proj: q = (query @ Wq^T + bq) * gq * QSCALE, bf16 out ----
    int w = tid >> 6; int l = tid & 63;
    int lr = l & 15, lc = l >> 4;
    int r0 = blockIdx.x * 64;
    f32x4 acc[16];
    #pragma unroll
    for(int n=0;n<16;n++) acc[n] = (f32x4){0.f,0.f,0.f,0.f};
    const float* qrow = query + (size_t)(r0 + w*16 + lr)*D;
    #pragma unroll
    for(int i=0;i<5;i++){ int c = i*256 + tid; gl_lds16(wq_g + c*8, (char*)smem[0] + c*16); }
    __syncthreads();
    int cur = 0;
    for(int kc=0; kc<8; kc++){
      if(kc < 7){
        #pragma unroll
        for(int i=0;i<5;i++){ int c = i*256 + tid;
          gl_lds16(wq_g + (size_t)(kc+1)*10240 + c*8, (char*)smem[cur^1] + c*16); }
      }
      bf16x8 af;
      {
        const float* s = qrow + kc*32 + lc*8;
        #pragma unroll
        for(int x=0;x<8;x++) af[x] = (short)f2bf(s[x]);
      }
      #pragma unroll
      for(int n=0;n<16;n++){
        bf16x8 bfrag = *(const bf16x8*)&smem[cur][(n*16 + lr)*40 + lc*8];
        acc[n] = __builtin_amdgcn_mfma_f32_16x16x32_bf16(af, bfrag, acc[n], 0, 0, 0);
      }
      __syncthreads();
      cur ^= 1;
    }
    #pragma unroll
    for(int n=0;n<16;n++){
      int col = n*16 + lr;
      float bb = bq[col], gg = gates[col] * QSCALE;
      #pragma unroll
      for(int r=0;r<4;r++){
        int row = r0 + w*16 + lc*4 + r;
        q_g[(size_t)row*D + col] = f2bf((acc[n][r] + bb) * gg);
      }
    }
  } else {
    // ---- prep1: K (row-padded) and V^T (k-permuted) via LDS transpose ----
    int bid2 = blockIdx.x - 256;
    int b = bid2 >> 7, jt = bid2 & 127;
    const float* vbase = value + ((size_t)b*T + jt*32)*D;
    const float* gk = gates + D;
    const float* vg = gates + 2*D;
    unsigned short* kt = k_g  + (size_t)bid2 * KT;
    unsigned short* vt = vt_g + (size_t)bid2 * VT;
    #pragma unroll
    for(int i=0;i<4;i++){
      int g = i*256 + tid; int j = g >> 5, c = g & 31;
      const float* src = vbase + j*D + c*8;
      bf16x8 pk;
      #pragma unroll
      for(int x=0;x<8;x++) pk[x] = (short)f2bf(src[x] * gk[c*8+x]);
      *(bf16x8*)&kt[j*264 + c*8] = pk;
    }
    float* lds = (float*)smem;   // [32][68]
    for(int c=0;c<4;c++){
      __syncthreads();
      {
        int row = tid >> 3, cg = tid & 7;
        const float* src = vbase + (size_t)row*D + c*64 + cg*8;
        f32x4 v0 = *(const f32x4*)src;
        f32x4 v1 = *(const f32x4*)(src + 4);
        *(f32x4*)&lds[row*68 + cg*8]     = v0;
        *(f32x4*)&lds[row*68 + cg*8 + 4] = v1;
      }
      __syncthreads();
      {
        int d0l = tid >> 2, u = tid & 3;
        int d0 = c*64 + d0l;
        float gd = vg[d0];
        bf16x8 pk;
        #pragma unroll
        for(int x=0;x<8;x++){
          int p = u*8 + x;
          int ksrc = ((p>>3)<<2) + (p&3) + (((p>>2)&1)<<4);  // PV A-frag k-perm
          pk[x] = (short)f2bf(lds[ksrc*68 + d0l] * gd);
        }
        *(bf16x8*)&vt[d0*40 + u*8] = pk;
      }
    }
  }
}

// ---------------- flash: single-buffered K+V (37.9KB LDS -> 4 blocks/CU) ----------------
// Loop: {barrier; stage(jt); vmcnt(0); barrier; compute(jt)} -- staging latency is
// covered by the OTHER 3 resident blocks (R8 showed own-block prefetch depth is moot).
// 4 waves x 32 q-rows (2 groups); exp2-domain softmax; cvt_pk packs; column-permuted parts.
__global__ __launch_bounds__(256, 4) void flash_kernel(
    const unsigned short* __restrict__ q_g,
    const unsigned short* __restrict__ k_g,
    const unsigned short* __restrict__ vt_g,
    unsigned short* __restrict__ parts,
    float* __restrict__ ml, int logS){
  __shared__ __align__(16) unsigned short kbuf[KT];
  __shared__ __align__(16) unsigned short vbuf[VT];
  int tid = threadIdx.x; int w = tid >> 6, l = tid & 63;
  int lr = l & 15, lc = l >> 4;
  int S = 1 << logS;
  int bid = blockIdx.x;
  int x = bid & 7; int b = x >> 1; int p = x & 1;   // XCD lane = (b, jt-half p)
  int item = bid >> 3;                              // heavy rblk first
  int half = S >> 1;
  int rblk = 31 - (item / half);
  int s = p*half + (item % half);
  int r0 = rblk * 128;
  int wrow0 = r0 + w*32;           // group A rows [wrow0,wrow0+16), B [+16,+32)
  int nt = 4*rblk + 4;
  int jt0 = (s*nt) >> logS, jt1 = ((s+1)*nt) >> logS;
  int grA = wrow0 + lr;
  int grB = wrow0 + 16 + lr;
  int diagA = (wrow0 + 15) >> 5;   // only tile needing causal cmp for group A
  int diagB = (wrow0 + 31) >> 5;

  bf16x8 qfA[8], qfB[8];
  {
    const unsigned short* qa = q_g + ((size_t)b*T + grA)*D + lc*8;
    const unsigned short* qb = q_g + ((size_t)b*T + grB)*D + lc*8;
    #pragma unroll
    for(int kc=0;kc<8;kc++){
      qfA[kc] = *(const bf16x8*)(qa + kc*32);
      qfB[kc] = *(const bf16x8*)(qb + kc*32);
    }
  }
  f32x4 oA[16], oB[16];
  #pragma unroll
  for(int n=0;n<16;n++){ oA[n] = (f32x4){0.f,0.f,0.f,0.f}; oB[n] = (f32x4){0.f,0.f,0.f,0.f}; }
  float mA = -INFINITY, lsA = 0.f, mB = -INFINITY, lsB = 0.f;

  const unsigned short* ktb = k_g  + (size_t)b*128*KT;
  const unsigned short* vtb = vt_g + (size_t)b*128*VT;

  for(int jt=jt0; jt<jt1; jt++){
    // barrier: all waves finished reading buf for jt-1
    __builtin_amdgcn_s_barrier();
    {
      const unsigned short* ks = ktb + (size_t)jt*KT;
      const unsigned short* vs = vtb + (size_t)jt*VT;
      for(int c=w; c<37; c+=4){
        if(c < 17) gl_lds16(ks + c*512 + l*8, (char*)kbuf + c*1024);
        else       gl_lds16(vs + (c-17)*512 + l*8, (char*)vbuf + (c-17)*1024);
      }
    }
    asm volatile("s_waitcnt vmcnt(0)" ::: "memory");
    __builtin_amdgcn_s_barrier();
    __builtin_amdgcn_sched_barrier(0);
    int j0 = jt*32;
    bool actA = (j0 <= wrow0 + 15);
    bool actB = (j0 <= wrow0 + 31);
    if(actB){
      f32x4 sA0={0,0,0,0}, sA1={0,0,0,0}, sB0={0,0,0,0}, sB1={0,0,0,0};
      if(actA){
        #pragma unroll
        for(int kc=0;kc<8;kc++){
          bf16x8 k0 = *(const bf16x8*)&kbuf[lr*264        + (kc*4 + lc)*8];
          bf16x8 k1 = *(const bf16x8*)&kbuf[(16 + lr)*264 + (kc*4 + lc)*8];
          sA0 = __builtin_amdgcn_mfma_f32_16x16x32_bf16(k0, qfA[kc], sA0, 0,0,0);
          sA1 = __builtin_amdgcn_mfma_f32_16x16x32_bf16(k1, qfA[kc], sA1, 0,0,0);
          sB0 = __builtin_amdgcn_mfma_f32_16x16x32_bf16(k0, qfB[kc], sB0, 0,0,0);
          sB1 = __builtin_amdgcn_mfma_f32_16x16x32_bf16(k1, qfB[kc], sB1, 0,0,0);
        }
      } else {
        #pragma unroll
        for(int kc=0;kc<8;kc++){
          bf16x8 k0 = *(const bf16x8*)&kbuf[lr*264        + (kc*4 + lc)*8];
          bf16x8 k1 = *(const bf16x8*)&kbuf[(16 + lr)*264 + (kc*4 + lc)*8];
          sB0 = __builtin_amdgcn_mfma_f32_16x16x32_bf16(k0, qfB[kc], sB0, 0,0,0);
          sB1 = __builtin_amdgcn_mfma_f32_16x16x32_bf16(k1, qfB[kc], sB1, 0,0,0);
        }
      }
      bf16x8 paA, paB;
      // ---- softmax group A (exp2 domain; scale folded into q) ----
      if(actA){
        float sv0[4], sv1[4];
        if(jt == diagA){
          #pragma unroll
          for(int r=0;r<4;r++){
            float x0 = sA0[r]; int gj0 = j0 + lc*4 + r;
            float x1 = sA1[r]; int gj1 = gj0 + 16;
            sv0[r] = (gj0 > grA || x0 == 0.0f) ? -INFINITY : x0;
            sv1[r] = (gj1 > grA || x1 == 0.0f) ? -INFINITY : x1;
          }
        } else {
          #pragma unroll
          for(int r=0;r<4;r++){
            sv0[r] = (sA0[r] == 0.0f) ? -INFINITY : sA0[r];
            sv1[r] = (sA1[r] == 0.0f) ? -INFINITY : sA1[r];
          }
        }
        float pmax = fmaxf(fmaxf(fmaxf(sv0[0],sv0[1]),fmaxf(sv0[2],sv0[3])),
                           fmaxf(fmaxf(sv1[0],sv1[1]),fmaxf(sv1[2],sv1[3])));
        pmax = fmaxf(pmax, __shfl_xor(pmax, 16));
        pmax = fmaxf(pmax, __shfl_xor(pmax, 32));
        bool mv = (pmax > mA + 11.5f);     // defer-max (8 nats in log2 domain)
        float mn = mv ? pmax : mA;
        float alpha = mv ? exp2f(mA - mn) : 1.0f;
        float p0[4], p1[4];
        #pragma unroll
        for(int r=0;r<4;r++){
          p0[r] = exp2f(sv0[r] - mn);
          p1[r] = exp2f(sv1[r] - mn);
        }
        if(__builtin_amdgcn_ballot_w64(mv)){
          float a0 = __shfl(alpha, lc*4 + 0);
          float a1 = __shfl(alpha, lc*4 + 1);
          float a2 = __shfl(alpha, lc*4 + 2);
          float a3 = __shfl(alpha, lc*4 + 3);
          #pragma unroll
          for(int n=0;n<16;n++){
            oA[n][0] *= a0; oA[n][1] *= a1; oA[n][2] *= a2; oA[n][3] *= a3;
          }
        }
        float ps = ((p0[0]+p0[1])+(p0[2]+p0[3])) + ((p1[0]+p1[1])+(p1[2]+p1[3]));
        lsA = lsA*alpha + ps;
        mA = mn;
        union { unsigned int u[4]; bf16x8 h; } pu;
        pu.u[0] = cvtpk(p0[0], p0[1]); pu.u[1] = cvtpk(p0[2], p0[3]);
        pu.u[2] = cvtpk(p1[0], p1[1]); pu.u[3] = cvtpk(p1[2], p1[3]);
        paA = pu.h;
      }
      // ---- softmax group B ----
      {
        float sv0[4], sv1[4];
        if(jt == diagB){
          #pragma unroll
          for(int r=0;r<4;r++){
            float x0 = sB0[r]; int gj0 = j0 + lc*4 + r;
            float x1 = sB1[r]; int gj1 = gj0 + 16;
            sv0[r] = (gj0 > grB || x0 == 0.0f) ? -INFINITY : x0;
            sv1[r] = (gj1 > grB || x1 == 0.0f) ? -INFINITY : x1;
          }
        } else {
          #pragma unroll
          for(int r=0;r<4;r++){
            sv0[r] = (sB0[r] == 0.0f) ? -INFINITY : sB0[r];
            sv1[r] = (sB1[r] == 0.0f) ? -INFINITY : sB1[r];
          }
        }
        float pmax = fmaxf(fmaxf(fmaxf(sv0[0],sv0[1]),fmaxf(sv0[2],sv0[3])),
                           fmaxf(fmaxf(sv1[0],sv1[1]),fmaxf(sv1[2],sv1[3])));
        pmax = fmaxf(pmax, __shfl_xor(pmax, 16));
        pmax = fmaxf(pmax, __shfl_xor(pmax, 32));
        bool mv = (pmax > mB + 11.5f);
        float mn = mv ? pmax : mB;
        float alpha = mv ? exp2f(mB - mn) : 1.0f;
        float p0[4], p1[4];
        #pragma unroll
        for(int r=0;r<4;r++){
          p0[r] = exp2f(sv0[r] - mn);
          p1[r] = exp2f(sv1[r] - mn);
        }
        if(__builtin_amdgcn_ballot_w64(mv)){
          float a0 = __shfl(alpha, lc*4 + 0);
          float a1 = __shfl(alpha, lc*4 + 1);
          float a2 = __shfl(alpha, lc*4 + 2);
          float a3 = __shfl(alpha, lc*4 + 3);
          #pragma unroll
          for(int n=0;n<16;n++){
            oB[n][0] *= a0; oB[n][1] *= a1; oB[n][2] *= a2; oB[n][3] *= a3;
          }
        }
        float ps = ((p0[0]+p0[1])+(p0[2]+p0[3])) + ((p1[0]+p1[1])+(p1[2]+p1[3]));
        lsB = lsB*alpha + ps;
        mB = mn;
        union { unsigned int u[4]; bf16x8 h; } pu;
        pu.u[0] = cvtpk(p0[0], p0[1]); pu.u[1] = cvtpk(p0[2], p0[3]);
        pu.u[2] = cvtpk(p1[0], p1[1]); pu.u[3] = cvtpk(p1[2], p1[3]);
        paB = pu.h;
      }
      // ---- PV: each V fragment read once, used by both groups ----
      if(actA){
        #pragma unroll
        for(int n=0;n<16;n++){
          bf16x8 vf = *(const bf16x8*)&vbuf[(n*16 + lr)*40 + lc*8];
          oA[n] = __builtin_amdgcn_mfma_f32_16x16x32_bf16(paA, vf, oA[n], 0,0,0);
          oB[n] = __builtin_amdgcn_mfma_f32_16x16x32_bf16(paB, vf, oB[n], 0,0,0);
        }
      } else {
        #pragma unroll
        for(int n=0;n<16;n++){
          bf16x8 vf = *(const bf16x8*)&vbuf[(n*16 + lr)*40 + lc*8];
          oB[n] = __builtin_amdgcn_mfma_f32_16x16x32_bf16(paB, vf, oB[n], 0,0,0);
        }
      }
    }
  }

  // epilogue: permuted bf16 partial via cvt_pk + b128 stores; (m, l) in log2 domain
  unsigned short* obase = parts + (size_t)s*PSTR + ((size_t)b*T + wrow0)*D;
  #pragma unroll
  for(int r=0;r<4;r++){
    int row = lc*4 + r;
    unsigned int wa[8], wb[8];
    #pragma unroll
    for(int k=0;k<8;k++){
      wa[k] = cvtpk(oA[2*k][r], oA[2*k+1][r]);
      wb[k] = cvtpk(oB[2*k][r], oB[2*k+1][r]);
    }
    *(u32x4*)&obase[(size_t)row*D + lr*16]          = (u32x4){wa[0],wa[1],wa[2],wa[3]};
    *(u32x4*)&obase[(size_t)row*D + lr*16 + 8]      = (u32x4){wa[4],wa[5],wa[6],wa[7]};
    *(u32x4*)&obase[(size_t)(row+16)*D + lr*16]     = (u32x4){wb[0],wb[1],wb[2],wb[3]};
    *(u32x4*)&obase[(size_t)(row+16)*D + lr*16 + 8] = (u32x4){wb[4],wb[5],wb[6],wb[7]};
  }
  lsA += __shfl_xor(lsA, 16); lsA += __shfl_xor(lsA, 32);
  lsB += __shfl_xor(lsB, 16); lsB += __shfl_xor(lsB, 32);
  if(l < 16){
    float* mlbA = ml + ((size_t)s*4*T + (size_t)b*T + wrow0 + lr)*2;
    mlbA[0] = mA; mlbA[1] = lsA;
    float* mlbB = ml + ((size_t)s*4*T + (size_t)b*T + wrow0 + 16 + lr)*2;
    mlbB[0] = mB; mlbB[1] = lsB;
  }
}

// ---------------- combine: thread = (row, lr); un-permutes parts; exp2 domain ----------------
__global__ __launch_bounds__(256) void combine_kernel(
    const unsigned short* __restrict__ parts, const float* __restrict__ ml,
    float* __restrict__ out, int S){
  int t = blockIdx.x*256 + threadIdx.x;   // [0, 4*T*16)
  int row = t >> 4;                       // b*T + row
  int lr  = t & 15;
  float msv[8], lsv[8];
  float mm = -INFINITY;
  #pragma unroll
  for(int s=0;s<8;s++){
    if(s >= S) break;
    msv[s] = ml[((size_t)s*4*T + row)*2];
    lsv[s] = ml[((size_t)s*4*T + row)*2 + 1];
    mm = fmaxf(mm, msv[s]);
  }
  float denom = 0.f;
  float acc[16];
  #pragma unroll
  for(int n=0;n<16;n++) acc[n] = 0.f;
  #pragma unroll
  for(int s=0;s<8;s++){
    if(s >= S) break;
    float as = exp2f(msv[s] - mm);
    if(as != 0.0f){
      denom += as*lsv[s];
      const unsigned short* src = parts + (size_t)s*PSTR + (size_t)row*D + lr*16;
      u16x8 v0 = *(const u16x8*)src;
      u16x8 v1 = *(const u16x8*)(src + 8);
      #pragma unroll
      for(int n=0;n<8;n++){ acc[n] += as*bf2f(v0[n]); acc[8+n] += as*bf2f(v1[n]); }
    }
  }
  float inv = 1.0f/denom;
  float* orow = out + (size_t)row*D;
  #pragma unroll
  for(int n=0;n<16;n++) orow[n*16 + lr] = acc[n]*inv;   // d = n*16+lr (un-permute)
}

extern "C" void kernel_launch(void* const* d_in, const int* in_sizes, int n_in,
                              void* d_out, int out_size, void* d_ws, size_t ws_size,
                              hipStream_t stream){
  (void)in_sizes; (void)n_in; (void)out_size;
  const float* query = (const float*)d_in[0];
  const float* value = (const float*)d_in[1];
  const float* q_vec = (const float*)d_in[2];
  const float* k_vec = (const float*)d_in[3];
  const float* v_vec = (const float*)d_in[4];
  const float* Wq    = (const float*)d_in[5];
  const float* bq    = (const float*)d_in[6];
  const float* Ws    = (const float*)d_in[7];
  const float* bs    = (const float*)d_in[8];
  const float* Wt    = (const float*)d_in[9];
  const float* bt    = (const float*)d_in[10];
  char* ws = (char*)d_ws;
  unsigned short* q_g  = (unsigned short*)(ws);             //  8,388,608 B
  unsigned short* k_g  = (unsigned short*)(ws + 8388608);   //  8,912,896 B
  unsigned short* vt_g = (unsigned short*)(ws + 17301504);  // 10,485,760 B
  unsigned short* wq_g = (unsigned short*)(ws + 27787264);  //    163,840 B
  float* gates         = (float*)(ws + 27951104);           //      4,096 B
  unsigned short* parts= (unsigned short*)(ws + 27955200);  // S*8,388,608 B
  float* out = (float*)d_out;

  size_t base = 27955200;
  size_t mlsz = (size_t)8*4*T*2*4;
  int logS;
  if(ws_size >= base + 8*PSTR*2 + mlsz)      logS = 3;
  else if(ws_size >= base + 4*PSTR*2 + mlsz) logS = 2;
  else                                       logS = 1;
  int S = 1 << logS;
  float* ml = (float*)(ws + base + (size_t)S*PSTR*2);

  hipLaunchKernelGGL(prep_kernel, dim3(9),   dim3(256), 0, stream,
                     q_vec, k_vec, v_vec, Ws, bs, Wt, bt, Wq, gates, wq_g);
  hipLaunchKernelGGL(mid_kernel,  dim3(768), dim3(256), 0, stream,
                     query, wq_g, bq, gates, q_g, value, k_g, vt_g);
  hipLaunchKernelGGL(flash_kernel, dim3(128*S), dim3(256), 0, stream,
                     q_g, k_g, vt_g, parts, ml, logS);
  hipLaunchKernelGGL(combine_kernel, dim3((4*T*16)/256), dim3(256), 0, stream,
                     parts, ml, out, S);
}

// Round 15
// 113.761 us; speedup vs baseline: 4.3838x; 4.3838x over previous
//
#include <hip/hip_runtime.h>
#include <math.h>

#define D 256
#define T 4096
#define KT (17408/2)       // shorts per K tile (stride incl. pad)
#define VT (20480/2)       // shorts per V^T tile
#define PSTR ((size_t)4*T*D)  // shorts per bf16 partial buffer

typedef __attribute__((ext_vector_type(8))) short bf16x8;
typedef __attribute__((ext_vector_type(4))) float f32x4;
typedef __attribute__((ext_vector_type(8))) unsigned short u16x8;
typedef __attribute__((ext_vector_type(4))) unsigned int u32x4;

// log2(e)/16: folds softmax 1/sqrt(D) scale AND exp->exp2 conversion into q
#define QSCALE 0.0901684850f

__device__ __forceinline__ unsigned short f2bf(float x){
  unsigned int u = __float_as_uint(x);
  unsigned int r = (u + 0x7FFFu + ((u >> 16) & 1u)) >> 16;
  return (unsigned short)r;
}
__device__ __forceinline__ float bf2f(unsigned short h){
  return __uint_as_float(((unsigned int)h) << 16);
}
__device__ __forceinline__ unsigned int cvtpk(float lo, float hi){
  unsigned int w;
  asm("v_cvt_pk_bf16_f32 %0, %1, %2" : "=v"(w) : "v"(lo), "v"(hi));
  return w;
}

__device__ __forceinline__ void gl_lds16(const void* g, void* l){
  __builtin_amdgcn_global_load_lds((const __attribute__((address_space(1))) unsigned int*)g,
                                   (__attribute__((address_space(3))) unsigned int*)l, 16, 0, 0);
}

// ---------------- prep: gates (block 0) + Wq bf16 image (blocks 1..8) ----------------
__global__ __launch_bounds__(256) void prep_kernel(
    const float* __restrict__ q_vec, const float* __restrict__ k_vec,
    const float* __restrict__ v_vec, const float* __restrict__ Ws,
    const float* __restrict__ bs, const float* __restrict__ Wt,
    const float* __restrict__ bt, const float* __restrict__ Wq,
    float* __restrict__ gates, unsigned short* __restrict__ wq_g){
  int t = threadIdx.x;
  if(blockIdx.x == 0){
    __shared__ float vv[D];
    vv[t]         = 1.f/(1.f + __expf(-v_vec[t]));
    gates[t]      = 1.f/(1.f + __expf(-q_vec[t]));   // gq
    gates[D + t]  = 1.f/(1.f + __expf(-k_vec[t]));   // gk
    __syncthreads();
    const f32x4* wsr = (const f32x4*)(Ws + (size_t)t*D);
    const f32x4* wtr = (const f32x4*)(Wt + (size_t)t*D);
    const f32x4* vvv = (const f32x4*)vv;
    f32x4 a0 = {0,0,0,0}, a1 = {0,0,0,0}, c0 = {0,0,0,0}, c1 = {0,0,0,0};
    for(int i=0;i<64;i+=2){
      f32x4 v0 = vvv[i], v1 = vvv[i+1];
      a0 += wsr[i]*v0; a1 += wsr[i+1]*v1;
      c0 += wtr[i]*v0; c1 += wtr[i+1]*v1;
    }
    f32x4 as = a0 + a1, cs = c0 + c1;
    float s1 = bs[t] + as[0]+as[1]+as[2]+as[3];
    float s2 = bt[t] + cs[0]+cs[1]+cs[2]+cs[3];
    gates[2*D + t] = (1.f/(1.f + __expf(-s1))) * tanhf(s2);  // v_gate
  } else {
    int kc = blockIdx.x - 1;
    const float* src = Wq + (size_t)t*D + kc*32;
    unsigned short* dst = wq_g + (size_t)kc*10240 + t*40;
    #pragma unroll
    for(int u=0;u<4;u++){
      bf16x8 pk;
      #pragma unroll
      for(int x=0;x<8;x++) pk[x] = (short)f2bf(src[u*8+x]);
      *(bf16x8*)&dst[u*8] = pk;
    }
  }
}

// ---------------- mid: proj (blocks 0..255) + prep1 (blocks 256..767) ----------------
__global__ __launch_bounds__(256) void mid_kernel(
    const float* __restrict__ query, const unsigned short* __restrict__ wq_g,
    const float* __restrict__ bq, const float* __restrict__ gates,
    unsigned short* __restrict__ q_g,
    const float* __restrict__ value,
    unsigned short* __restrict__ k_g, unsigned short* __restrict__ vt_g){
  __shared__ __align__(16) unsigned short smem[2][10240];
  int tid = threadIdx.x;
  if(blockIdx.x < 256){
    // ---- proj: q = (query @ Wq^T + bq) * gq * QSCALE, bf16 out ----
    int w = tid >> 6; int l = tid & 63;
    int lr = l & 15, lc = l >> 4;
    int r0 = blockIdx.x * 64;
    f32x4 acc[16];
    #pragma unroll
    for(int n=0;n<16;n++) acc[n] = (f32x4){0.f,0.f,0.f,0.f};
    const float* qrow = query + (size_t)(r0 + w*16 + lr)*D;
    #pragma unroll
    for(int i=0;i<5;i++){ int c = i*256 + tid; gl_lds16(wq_g + c*8, (char*)smem[0] + c*16); }
    __syncthreads();
    int cur = 0;
    for(int kc=0; kc<8; kc++){
      if(kc < 7){
        #pragma unroll
        for(int i=0;i<5;i++){ int c = i*256 + tid;
          gl_lds16(wq_g + (size_t)(kc+1)*10240 + c*8, (char*)smem[cur^1] + c*16); }
      }
      bf16x8 af;
      {
        const float* s = qrow + kc*32 + lc*8;
        #pragma unroll
        for(int x=0;x<8;x++) af[x] = (short)f2bf(s[x]);
      }
      #pragma unroll
      for(int n=0;n<16;n++){
        bf16x8 bfrag = *(const bf16x8*)&smem[cur][(n*16 + lr)*40 + lc*8];
        acc[n] = __builtin_amdgcn_mfma_f32_16x16x32_bf16(af, bfrag, acc[n], 0, 0, 0);
      }
      __syncthreads();
      cur ^= 1;
    }
    #pragma unroll
    for(int n=0;n<16;n++){
      int col = n*16 + lr;
      float bb = bq[col], gg = gates[col] * QSCALE;
      #pragma unroll
      for(int r=0;r<4;r++){
        int row = r0 + w*16 + lc*4 + r;
        q_g[(size_t)row*D + col] = f2bf((acc[n][r] + bb) * gg);
      }
    }
  } else {
    // ---- prep1: K (row-padded) and V^T (k-permuted) via LDS transpose ----
    int bid2 = blockIdx.x - 256;
    int b = bid2 >> 7, jt = bid2 & 127;
    const float* vbase = value + ((size_t)b*T + jt*32)*D;
    const float* gk = gates + D;
    const float* vg = gates + 2*D;
    unsigned short* kt = k_g  + (size_t)bid2 * KT;
    unsigned short* vt = vt_g + (size_t)bid2 * VT;
    #pragma unroll
    for(int i=0;i<4;i++){
      int g = i*256 + tid; int j = g >> 5, c = g & 31;
      const float* src = vbase + j*D + c*8;
      bf16x8 pk;
      #pragma unroll
      for(int x=0;x<8;x++) pk[x] = (short)f2bf(src[x] * gk[c*8+x]);
      *(bf16x8*)&kt[j*264 + c*8] = pk;
    }
    float* lds = (float*)smem;   // [32][68]
    for(int c=0;c<4;c++){
      __syncthreads();
      {
        int row = tid >> 3, cg = tid & 7;
        const float* src = vbase + (size_t)row*D + c*64 + cg*8;
        f32x4 v0 = *(const f32x4*)src;
        f32x4 v1 = *(const f32x4*)(src + 4);
        *(f32x4*)&lds[row*68 + cg*8]     = v0;
        *(f32x4*)&lds[row*68 + cg*8 + 4] = v1;
      }
      __syncthreads();
      {
        int d0l = tid >> 2, u = tid & 3;
        int d0 = c*64 + d0l;
        float gd = vg[d0];
        bf16x8 pk;
        #pragma unroll
        for(int x=0;x<8;x++){
          int p = u*8 + x;
          int ksrc = ((p>>3)<<2) + (p&3) + (((p>>2)&1)<<4);  // PV A-frag k-perm
          pk[x] = (short)f2bf(lds[ksrc*68 + d0l] * gd);
        }
        *(bf16x8*)&vt[d0*40 + u*8] = pk;
      }
    }
  }
}

// ---------------- flash: 4 waves x 32 q-rows (2 groups); exp2-domain softmax; cvt_pk packs ----------------
// parts layout is COLUMN-PERMUTED: value for d = n*16+lr stored at short-index lr*16+n
// (lets each lane store 2x b128 instead of 32 u16 stores; combine inverts).
__global__ __launch_bounds__(256, 2) void flash_kernel(
    const unsigned short* __restrict__ q_g,
    const unsigned short* __restrict__ k_g,
    const unsigned short* __restrict__ vt_g,
    unsigned short* __restrict__ parts,
    float* __restrict__ ml, int logS){
  __shared__ __align__(16) unsigned short kbuf[2][KT];
  __shared__ __align__(16) unsigned short vbuf[2][VT];
  int tid = threadIdx.x; int w = tid >> 6, l = tid & 63;
  int lr = l & 15, lc = l >> 4;
  int S = 1 << logS;
  int bid = blockIdx.x;
  int x = bid & 7; int b = x >> 1; int p = x & 1;   // XCD lane = (b, jt-half p)
  int item = bid >> 3;                              // heavy rblk first
  int half = S >> 1;
  int rblk = 31 - (item / half);
  int s = p*half + (item % half);
  int r0 = rblk * 128;
  int wrow0 = r0 + w*32;           // group A rows [wrow0,wrow0+16), B [+16,+32)
  int nt = 4*rblk + 4;
  int jt0 = (s*nt) >> logS, jt1 = ((s+1)*nt) >> logS;
  int grA = wrow0 + lr;
  int grB = wrow0 + 16 + lr;
  int diagA = (wrow0 + 15) >> 5;   // only tile needing causal cmp for group A
  int diagB = (wrow0 + 31) >> 5;

  bf16x8 qfA[8], qfB[8];
  {
    const unsigned short* qa = q_g + ((size_t)b*T + grA)*D + lc*8;
    const unsigned short* qb = q_g + ((size_t)b*T + grB)*D + lc*8;
    #pragma unroll
    for(int kc=0;kc<8;kc++){
      qfA[kc] = *(const bf16x8*)(qa + kc*32);
      qfB[kc] = *(const bf16x8*)(qb + kc*32);
    }
  }
  f32x4 oA[16], oB[16];
  #pragma unroll
  for(int n=0;n<16;n++){ oA[n] = (f32x4){0.f,0.f,0.f,0.f}; oB[n] = (f32x4){0.f,0.f,0.f,0.f}; }
  float mA = -INFINITY, lsA = 0.f, mB = -INFINITY, lsB = 0.f;

  const unsigned short* ktb = k_g  + (size_t)b*128*KT;
  const unsigned short* vtb = vt_g + (size_t)b*128*VT;

  if(jt1 > jt0){
    const unsigned short* ks = ktb + (size_t)jt0*KT;
    const unsigned short* vs = vtb + (size_t)jt0*VT;
    for(int c=w; c<37; c+=4){
      if(c < 17) gl_lds16(ks + c*512 + l*8, (char*)kbuf[jt0&1] + c*1024);
      else       gl_lds16(vs + (c-17)*512 + l*8, (char*)vbuf[jt0&1] + (c-17)*1024);
    }
  }

  for(int jt=jt0; jt<jt1; jt++){
    int cur = jt & 1;
    asm volatile("s_waitcnt vmcnt(0)" ::: "memory");
    __builtin_amdgcn_s_barrier();
    __builtin_amdgcn_sched_barrier(0);
    if(jt+1 < jt1){
      const unsigned short* ks = ktb + (size_t)(jt+1)*KT;
      const unsigned short* vs = vtb + (size_t)(jt+1)*VT;
      for(int c=w; c<37; c+=4){
        if(c < 17) gl_lds16(ks + c*512 + l*8, (char*)kbuf[cur^1] + c*1024);
        else       gl_lds16(vs + (c-17)*512 + l*8, (char*)vbuf[cur^1] + (c-17)*1024);
      }
    }
    int j0 = jt*32;
    bool actA = (j0 <= wrow0 + 15);
    bool actB = (j0 <= wrow0 + 31);
    if(actB){
      f32x4 sA0={0,0,0,0}, sA1={0,0,0,0}, sB0={0,0,0,0}, sB1={0,0,0,0};
      if(actA){
        #pragma unroll
        for(int kc=0;kc<8;kc++){
          bf16x8 k0 = *(const bf16x8*)&kbuf[cur][lr*264        + (kc*4 + lc)*8];
          bf16x8 k1 = *(const bf16x8*)&kbuf[cur][(16 + lr)*264 + (kc*4 + lc)*8];
          sA0 = __builtin_amdgcn_mfma_f32_16x16x32_bf16(k0, qfA[kc], sA0, 0,0,0);
          sA1 = __builtin_amdgcn_mfma_f32_16x16x32_bf16(k1, qfA[kc], sA1, 0,0,0);
          sB0 = __builtin_amdgcn_mfma_f32_16x16x32_bf16(k0, qfB[kc], sB0, 0,0,0);
          sB1 = __builtin_amdgcn_mfma_f32_16x16x32_bf16(k1, qfB[kc], sB1, 0,0,0);
        }
      } else {
        #pragma unroll
        for(int kc=0;kc<8;kc++){
          bf16x8 k0 = *(const bf16x8*)&kbuf[cur][lr*264        + (kc*4 + lc)*8];
          bf16x8 k1 = *(const bf16x8*)&kbuf[cur][(16 + lr)*264 + (kc*4 + lc)*8];
          sB0 = __builtin_amdgcn_mfma_f32_16x16x32_bf16(k0, qfB[kc], sB0, 0,0,0);
          sB1 = __builtin_amdgcn_mfma_f32_16x16x32_bf16(k1, qfB[kc], sB1, 0,0,0);
        }
      }
      bf16x8 paA, paB;
      // ---- softmax group A (exp2 domain; scale folded into q) ----
      if(actA){
        float sv0[4], sv1[4];
        if(jt == diagA){
          #pragma unroll
          for(int r=0;r<4;r++){
            float x0 = sA0[r]; int gj0 = j0 + lc*4 + r;
            float x1 = sA1[r]; int gj1 = gj0 + 16;
            sv0[r] = (gj0 > grA || x0 == 0.0f) ? -INFINITY : x0;
            sv1[r] = (gj1 > grA || x1 == 0.0f) ? -INFINITY : x1;
          }
        } else {
          #pragma unroll
          for(int r=0;r<4;r++){
            sv0[r] = (sA0[r] == 0.0f) ? -INFINITY : sA0[r];
            sv1[r] = (sA1[r] == 0.0f) ? -INFINITY : sA1[r];
          }
        }
        float pmax = fmaxf(fmaxf(fmaxf(sv0[0],sv0[1]),fmaxf(sv0[2],sv0[3])),
                           fmaxf(fmaxf(sv1[0],sv1[1]),fmaxf(sv1[2],sv1[3])));
        pmax = fmaxf(pmax, __shfl_xor(pmax, 16));
        pmax = fmaxf(pmax, __shfl_xor(pmax, 32));
        bool mv = (pmax > mA + 11.5f);     // defer-max (8 nats in log2 domain)
        float mn = mv ? pmax : mA;
        float alpha = mv ? exp2f(mA - mn) : 1.0f;
        float p0[4], p1[4];
        #pragma unroll
        for(int r=0;r<4;r++){
          p0[r] = exp2f(sv0[r] - mn);
          p1[r] = exp2f(sv1[r] - mn);
        }
        if(__builtin_amdgcn_ballot_w64(mv)){
          float a0 = __shfl(alpha, lc*4 + 0);
          float a1 = __shfl(alpha, lc*4 + 1);
          float a2 = __shfl(alpha, lc*4 + 2);
          float a3 = __shfl(alpha, lc*4 + 3);
          #pragma unroll
          for(int n=0;n<16;n++){
            oA[n][0] *= a0; oA[n][1] *= a1; oA[n][2] *= a2; oA[n][3] *= a3;
          }
        }
        float ps = ((p0[0]+p0[1])+(p0[2]+p0[3])) + ((p1[0]+p1[1])+(p1[2]+p1[3]));
        lsA = lsA*alpha + ps;
        mA = mn;
        union { unsigned int u[4]; bf16x8 h; } pu;
        pu.u[0] = cvtpk(p0[0], p0[1]); pu.u[1] = cvtpk(p0[2], p0[3]);
        pu.u[2] = cvtpk(p1[0], p1[1]); pu.u[3] = cvtpk(p1[2], p1[3]);
        paA = pu.h;
      }
      // ---- softmax group B ----
      {
        float sv0[4], sv1[4];
        if(jt == diagB){
          #pragma unroll
          for(int r=0;r<4;r++){
            float x0 = sB0[r]; int gj0 = j0 + lc*4 + r;
            float x1 = sB1[r]; int gj1 = gj0 + 16;
            sv0[r] = (gj0 > grB || x0 == 0.0f) ? -INFINITY : x0;
            sv1[r] = (gj1 > grB || x1 == 0.0f) ? -INFINITY : x1;
          }
        } else {
          #pragma unroll
          for(int r=0;r<4;r++){
            sv0[r] = (sB0[r] == 0.0f) ? -INFINITY : sB0[r];
            sv1[r] = (sB1[r] == 0.0f) ? -INFINITY : sB1[r];
          }
        }
        float pmax = fmaxf(fmaxf(fmaxf(sv0[0],sv0[1]),fmaxf(sv0[2],sv0[3])),
                           fmaxf(fmaxf(sv1[0],sv1[1]),fmaxf(sv1[2],sv1[3])));
        pmax = fmaxf(pmax, __shfl_xor(pmax, 16));
        pmax = fmaxf(pmax, __shfl_xor(pmax, 32));
        bool mv = (pmax > mB + 11.5f);
        float mn = mv ? pmax : mB;
        float alpha = mv ? exp2f(mB - mn) : 1.0f;
        float p0[4], p1[4];
        #pragma unroll
        for(int r=0;r<4;r++){
          p0[r] = exp2f(sv0[r] - mn);
          p1[r] = exp2f(sv1[r] - mn);
        }
        if(__builtin_amdgcn_ballot_w64(mv)){
          float a0 = __shfl(alpha, lc*4 + 0);
          float a1 = __shfl(alpha, lc*4 + 1);
          float a2 = __shfl(alpha, lc*4 + 2);
          float a3 = __shfl(alpha, lc*4 + 3);
          #pragma unroll
          for(int n=0;n<16;n++){
            oB[n][0] *= a0; oB[n][1] *= a1; oB[n][2] *= a2; oB[n][3] *= a3;
          }
        }
        float ps = ((p0[0]+p0[1])+(p0[2]+p0[3])) + ((p1[0]+p1[1])+(p1[2]+p1[3]));
        lsB = lsB*alpha + ps;
        mB = mn;
        union { unsigned int u[4]; bf16x8 h; } pu;
        pu.u[0] = cvtpk(p0[0], p0[1]); pu.u[1] = cvtpk(p0[2], p0[3]);
        pu.u[2] = cvtpk(p1[0], p1[1]); pu.u[3] = cvtpk(p1[2], p1[3]);
        paB = pu.h;
      }
      // ---- PV: each V fragment read once, used by both groups ----
      if(actA){
        #pragma unroll
        for(int n=0;n<16;n++){
          bf16x8 vf = *(const bf16x8*)&vbuf[cur][(n*16 + lr)*40 + lc*8];
          oA[n] = __builtin_amdgcn_mfma_f32_16x16x32_bf16(paA, vf, oA[n], 0,0,0);
          oB[n] = __builtin_amdgcn_mfma_f32_16x16x32_bf16(paB, vf, oB[n], 0,0,0);
        }
      } else {
        #pragma unroll
        for(int n=0;n<16;n++){
          bf16x8 vf = *(const bf16x8*)&vbuf[cur][(n*16 + lr)*40 + lc*8];
          oB[n] = __builtin_amdgcn_mfma_f32_16x16x32_bf16(paB, vf, oB[n], 0,0,0);
        }
      }
    }
  }

  // epilogue: permuted bf16 partial via cvt_pk + b128 stores; (m, l) in log2 domain
  unsigned short* obase = parts + (size_t)s*PSTR + ((size_t)b*T + wrow0)*D;
  #pragma unroll
  for(int r=0;r<4;r++){
    int row = lc*4 + r;
    unsigned int wa[8], wb[8];
    #pragma unroll
    for(int k=0;k<8;k++){
      wa[k] = cvtpk(oA[2*k][r], oA[2*k+1][r]);
      wb[k] = cvtpk(oB[2*k][r], oB[2*k+1][r]);
    }
    *(u32x4*)&obase[(size_t)row*D + lr*16]          = (u32x4){wa[0],wa[1],wa[2],wa[3]};
    *(u32x4*)&obase[(size_t)row*D + lr*16 + 8]      = (u32x4){wa[4],wa[5],wa[6],wa[7]};
    *(u32x4*)&obase[(size_t)(row+16)*D + lr*16]     = (u32x4){wb[0],wb[1],wb[2],wb[3]};
    *(u32x4*)&obase[(size_t)(row+16)*D + lr*16 + 8] = (u32x4){wb[4],wb[5],wb[6],wb[7]};
  }
  lsA += __shfl_xor(lsA, 16); lsA += __shfl_xor(lsA, 32);
  lsB += __shfl_xor(lsB, 16); lsB += __shfl_xor(lsB, 32);
  if(l < 16){
    float* mlbA = ml + ((size_t)s*4*T + (size_t)b*T + wrow0 + lr)*2;
    mlbA[0] = mA; mlbA[1] = lsA;
    float* mlbB = ml + ((size_t)s*4*T + (size_t)b*T + wrow0 + 16 + lr)*2;
    mlbB[0] = mB; mlbB[1] = lsB;
  }
}

// ---------------- combine: thread = (row, lr); un-permutes parts; exp2 domain ----------------
__global__ __launch_bounds__(256) void combine_kernel(
    const unsigned short* __restrict__ parts, const float* __restrict__ ml,
    float* __restrict__ out, int S){
  int t = blockIdx.x*256 + threadIdx.x;   // [0, 4*T*16)
  int row = t >> 4;                       // b*T + row
  int lr  = t & 15;
  float msv[8], lsv[8];
  float mm = -INFINITY;
  #pragma unroll
  for(int s=0;s<8;s++){
    if(s >= S) break;
    msv[s] = ml[((size_t)s*4*T + row)*2];
    lsv[s] = ml[((size_t)s*4*T + row)*2 + 1];
    mm = fmaxf(mm, msv[s]);
  }
  float denom = 0.f;
  float acc[16];
  #pragma unroll
  for(int n=0;n<16;n++) acc[n] = 0.f;
  #pragma unroll
  for(int s=0;s<8;s++){
    if(s >= S) break;
    float as = exp2f(msv[s] - mm);
    if(as != 0.0f){
      denom += as*lsv[s];
      const unsigned short* src = parts + (size_t)s*PSTR + (size_t)row*D + lr*16;
      u16x8 v0 = *(const u16x8*)src;
      u16x8 v1 = *(const u16x8*)(src + 8);
      #pragma unroll
      for(int n=0;n<8;n++){ acc[n] += as*bf2f(v0[n]); acc[8+n] += as*bf2f(v1[n]); }
    }
  }
  float inv = 1.0f/denom;
  float* orow = out + (size_t)row*D;
  #pragma unroll
  for(int n=0;n<16;n++) orow[n*16 + lr] = acc[n]*inv;   // d = n*16+lr (un-permute)
}

extern "C" void kernel_launch(void* const* d_in, const int* in_sizes, int n_in,
                              void* d_out, int out_size, void* d_ws, size_t ws_size,
                              hipStream_t stream){
  (void)in_sizes; (void)n_in; (void)out_size;
  const float* query = (const float*)d_in[0];
  const float* value = (const float*)d_in[1];
  const float* q_vec = (const float*)d_in[2];
  const float* k_vec = (const float*)d_in[3];
  const float* v_vec = (const float*)d_in[4];
  const float* Wq    = (const float*)d_in[5];
  const float* bq    = (const float*)d_in[6];
  const float* Ws    = (const float*)d_in[7];
  const float* bs    = (const float*)d_in[8];
  const float* Wt    = (const float*)d_in[9];
  const float* bt    = (const float*)d_in[10];
  char* ws = (char*)d_ws;
  unsigned short* q_g  = (unsigned short*)(ws);             //  8,388,608 B
  unsigned short* k_g  = (unsigned short*)(ws + 8388608);   //  8,912,896 B
  unsigned short* vt_g = (unsigned short*)(ws + 17301504);  // 10,485,760 B
  unsigned short* wq_g = (unsigned short*)(ws + 27787264);  //    163,840 B
  float* gates         = (float*)(ws + 27951104);           //      4,096 B
  unsigned short* parts= (unsigned short*)(ws + 27955200);  // S*8,388,608 B
  float* out = (float*)d_out;

  size_t base = 27955200;
  size_t mlsz = (size_t)8*4*T*2*4;
  int logS;
  if(ws_size >= base + 8*PSTR*2 + mlsz)      logS = 3;
  else if(ws_size >= base + 4*PSTR*2 + mlsz) logS = 2;
  else                                       logS = 1;
  int S = 1 << logS;
  float* ml = (float*)(ws + base + (size_t)S*PSTR*2);

  hipLaunchKernelGGL(prep_kernel, dim3(9),   dim3(256), 0, stream,
                     q_vec, k_vec, v_vec, Ws, bs, Wt, bt, Wq, gates, wq_g);
  hipLaunchKernelGGL(mid_kernel,  dim3(768), dim3(256), 0, stream,
                     query, wq_g, bq, gates, q_g, value, k_g, vt_g);
  hipLaunchKernelGGL(flash_kernel, dim3(128*S), dim3(256), 0, stream,
                     q_g, k_g, vt_g, parts, ml, logS);
  hipLaunchKernelGGL(combine_kernel, dim3((4*T*16)/256), dim3(256), 0, stream,
                     parts, ml, out, S);
}

// Round 16
// 111.890 us; speedup vs baseline: 4.4570x; 1.0167x over previous
//
#include <hip/hip_runtime.h>
#include <math.h>

#define D 256
#define T 4096
#define KTB 8192           // BYTES per fp8 K tile (32 rows x 256B, swizzled)
#define VT (20480/2)       // shorts per V^T tile
#define PSTR ((size_t)4*T*D)  // shorts per bf16 partial buffer

typedef __attribute__((ext_vector_type(8))) short bf16x8;
typedef __attribute__((ext_vector_type(4))) float f32x4;
typedef __attribute__((ext_vector_type(8))) unsigned short u16x8;
typedef __attribute__((ext_vector_type(4))) unsigned int u32x4;

// log2(e)/16: softmax 1/sqrt(D) scale AND exp->exp2 conversion (applied to scores)
#define QSCALE 0.0901684850f

__device__ __forceinline__ unsigned short f2bf(float x){
  unsigned int u = __float_as_uint(x);
  unsigned int r = (u + 0x7FFFu + ((u >> 16) & 1u)) >> 16;
  return (unsigned short)r;
}
__device__ __forceinline__ float bf2f(unsigned short h){
  return __uint_as_float(((unsigned int)h) << 16);
}
__device__ __forceinline__ unsigned int cvtpk(float lo, float hi){
  unsigned int w;
  asm("v_cvt_pk_bf16_f32 %0, %1, %2" : "=v"(w) : "v"(lo), "v"(hi));
  return w;
}
// 2x f32 -> 2x fp8 e4m3 in bits [15:0] (upper bits undefined; callers mask)
__device__ __forceinline__ unsigned int cvtpk8(float lo, float hi){
  unsigned int w;
  asm("v_cvt_pk_fp8_f32 %0, %1, %2" : "=v"(w) : "v"(lo), "v"(hi));
  return w;
}

__device__ __forceinline__ void gl_lds16(const void* g, void* l){
  __builtin_amdgcn_global_load_lds((const __attribute__((address_space(1))) unsigned int*)g,
                                   (__attribute__((address_space(3))) unsigned int*)l, 16, 0, 0);
}

// ---------------- prep: gates (block 0) + Wq bf16 image (blocks 1..8) ----------------
__global__ __launch_bounds__(256) void prep_kernel(
    const float* __restrict__ q_vec, const float* __restrict__ k_vec,
    const float* __restrict__ v_vec, const float* __restrict__ Ws,
    const float* __restrict__ bs, const float* __restrict__ Wt,
    const float* __restrict__ bt, const float* __restrict__ Wq,
    float* __restrict__ gates, unsigned short* __restrict__ wq_g){
  int t = threadIdx.x;
  if(blockIdx.x == 0){
    __shared__ float vv[D];
    vv[t]         = 1.f/(1.f + __expf(-v_vec[t]));
    gates[t]      = 1.f/(1.f + __expf(-q_vec[t]));   // gq
    gates[D + t]  = 1.f/(1.f + __expf(-k_vec[t]));   // gk
    __syncthreads();
    const f32x4* wsr = (const f32x4*)(Ws + (size_t)t*D);
    const f32x4* wtr = (const f32x4*)(Wt + (size_t)t*D);
    const f32x4* vvv = (const f32x4*)vv;
    f32x4 a0 = {0,0,0,0}, a1 = {0,0,0,0}, c0 = {0,0,0,0}, c1 = {0,0,0,0};
    for(int i=0;i<64;i+=2){
      f32x4 v0 = vvv[i], v1 = vvv[i+1];
      a0 += wsr[i]*v0; a1 += wsr[i+1]*v1;
      c0 += wtr[i]*v0; c1 += wtr[i+1]*v1;
    }
    f32x4 as = a0 + a1, cs = c0 + c1;
    float s1 = bs[t] + as[0]+as[1]+as[2]+as[3];
    float s2 = bt[t] + cs[0]+cs[1]+cs[2]+cs[3];
    gates[2*D + t] = (1.f/(1.f + __expf(-s1))) * tanhf(s2);  // v_gate
  } else {
    int kc = blockIdx.x - 1;
    const float* src = Wq + (size_t)t*D + kc*32;
    unsigned short* dst = wq_g + (size_t)kc*10240 + t*40;
    #pragma unroll
    for(int u=0;u<4;u++){
      bf16x8 pk;
      #pragma unroll
      for(int x=0;x<8;x++) pk[x] = (short)f2bf(src[u*8+x]);
      *(bf16x8*)&dst[u*8] = pk;
    }
  }
}

// ---------------- mid: proj (blocks 0..255) + prep1 (blocks 256..767) ----------------
// proj output q is fp8 e4m3 (natural scale; QSCALE applied to scores in flash).
// K stored fp8 e4m3 in a pre-swizzled image: byte (c*8)^((row&7)<<3) within 256B rows.
__global__ __launch_bounds__(256) void mid_kernel(
    const float* __restrict__ query, const unsigned short* __restrict__ wq_g,
    const float* __restrict__ bq, const float* __restrict__ gates,
    unsigned char* __restrict__ q8,
    const float* __restrict__ value,
    unsigned char* __restrict__ k8, unsigned short* __restrict__ vt_g){
  __shared__ __align__(16) unsigned short smem[2][10240];
  int tid = threadIdx.x;
  if(blockIdx.x < 256){
    // ---- proj: q = (query @ Wq^T + bq) * gq, fp8 out ----
    int w = tid >> 6; int l = tid & 63;
    int lr = l & 15, lc = l >> 4;
    int r0 = blockIdx.x * 64;
    f32x4 acc[16];
    #pragma unroll
    for(int n=0;n<16;n++) acc[n] = (f32x4){0.f,0.f,0.f,0.f};
    const float* qrow = query + (size_t)(r0 + w*16 + lr)*D;
    #pragma unroll
    for(int i=0;i<5;i++){ int c = i*256 + tid; gl_lds16(wq_g + c*8, (char*)smem[0] + c*16); }
    __syncthreads();
    int cur = 0;
    for(int kc=0; kc<8; kc++){
      if(kc < 7){
        #pragma unroll
        for(int i=0;i<5;i++){ int c = i*256 + tid;
          gl_lds16(wq_g + (size_t)(kc+1)*10240 + c*8, (char*)smem[cur^1] + c*16); }
      }
      bf16x8 af;
      {
        const float* s = qrow + kc*32 + lc*8;
        #pragma unroll
        for(int x=0;x<8;x++) af[x] = (short)f2bf(s[x]);
      }
      #pragma unroll
      for(int n=0;n<16;n++){
        bf16x8 bfrag = *(const bf16x8*)&smem[cur][(n*16 + lr)*40 + lc*8];
        acc[n] = __builtin_amdgcn_mfma_f32_16x16x32_bf16(af, bfrag, acc[n], 0, 0, 0);
      }
      __syncthreads();
      cur ^= 1;
    }
    #pragma unroll
    for(int n=0;n<16;n++){
      int col = n*16 + lr;
      float bb = bq[col], gg = gates[col];
      float v0 = (acc[n][0] + bb) * gg;
      float v1 = (acc[n][1] + bb) * gg;
      float v2 = (acc[n][2] + bb) * gg;
      float v3 = (acc[n][3] + bb) * gg;
      unsigned int wlo = cvtpk8(v0, v1);
      unsigned int whi = cvtpk8(v2, v3);
      int row0 = r0 + w*16 + lc*4;
      q8[(size_t)(row0+0)*D + col] = (unsigned char)(wlo);
      q8[(size_t)(row0+1)*D + col] = (unsigned char)(wlo >> 8);
      q8[(size_t)(row0+2)*D + col] = (unsigned char)(whi);
      q8[(size_t)(row0+3)*D + col] = (unsigned char)(whi >> 8);
    }
  } else {
    // ---- prep1: K fp8 (swizzled 256B rows) and V^T bf16 (k-permuted) ----
    int bid2 = blockIdx.x - 256;
    int b = bid2 >> 7, jt = bid2 & 127;
    const float* vbase = value + ((size_t)b*T + jt*32)*D;
    const float* gk = gates + D;
    const float* vg = gates + 2*D;
    unsigned char* kt = k8 + (size_t)bid2 * KTB;
    unsigned short* vt = vt_g + (size_t)bid2 * VT;
    #pragma unroll
    for(int i=0;i<4;i++){
      int g = i*256 + tid; int j = g >> 5, c = g & 31;
      const float* src = vbase + j*D + c*8;
      float f[8];
      #pragma unroll
      for(int x=0;x<8;x++) f[x] = src[x] * gk[c*8+x];
      unsigned int a0 = cvtpk8(f[0], f[1]);
      unsigned int a1 = cvtpk8(f[2], f[3]);
      unsigned int a2 = cvtpk8(f[4], f[5]);
      unsigned int a3 = cvtpk8(f[6], f[7]);
      unsigned long lo = (unsigned long)((a0 & 0xffffu) | (a1 << 16));
      unsigned long hi = (unsigned long)((a2 & 0xffffu) | (a3 << 16));
      unsigned int off = (unsigned)(c*8) ^ (unsigned)((j & 7) << 3);
      *(unsigned long*)&kt[(size_t)j*256 + off] = lo | (hi << 32);
    }
    float* lds = (float*)smem;   // [32][68]
    for(int c=0;c<4;c++){
      __syncthreads();
      {
        int row = tid >> 3, cg = tid & 7;
        const float* src = vbase + (size_t)row*D + c*64 + cg*8;
        f32x4 v0 = *(const f32x4*)src;
        f32x4 v1 = *(const f32x4*)(src + 4);
        *(f32x4*)&lds[row*68 + cg*8]     = v0;
        *(f32x4*)&lds[row*68 + cg*8 + 4] = v1;
      }
      __syncthreads();
      {
        int d0l = tid >> 2, u = tid & 3;
        int d0 = c*64 + d0l;
        float gd = vg[d0];
        bf16x8 pk;
        #pragma unroll
        for(int x=0;x<8;x++){
          int p = u*8 + x;
          int ksrc = ((p>>3)<<2) + (p&3) + (((p>>2)&1)<<4);  // PV A-frag k-perm
          pk[x] = (short)f2bf(lds[ksrc*68 + d0l] * gd);
        }
        *(bf16x8*)&vt[d0*40 + u*8] = pk;
      }
    }
  }
}

// ---------------- flash: 4 waves x 32 q-rows; fp8 QK^T, bf16 PV ----------------
// K LDS image swizzled (byte ^ (row&7)<<3); b64 fragment reads ~2-way banks.
// parts column-permuted as before; exp2-domain softmax (QSCALE on scores).
__global__ __launch_bounds__(256, 2) void flash_kernel(
    const unsigned char* __restrict__ q8,
    const unsigned char* __restrict__ k8,
    const unsigned short* __restrict__ vt_g,
    unsigned short* __restrict__ parts,
    float* __restrict__ ml, int logS){
  __shared__ __align__(16) unsigned char kbuf8[2][KTB];
  __shared__ __align__(16) unsigned short vbuf[2][VT];
  int tid = threadIdx.x; int w = tid >> 6, l = tid & 63;
  int lr = l & 15, lc = l >> 4;
  int S = 1 << logS;
  int bid = blockIdx.x;
  int x = bid & 7; int b = x >> 1; int p = x & 1;   // XCD lane = (b, jt-half p)
  int item = bid >> 3;                              // heavy rblk first
  int half = S >> 1;
  int rblk = 31 - (item / half);
  int s = p*half + (item % half);
  int r0 = rblk * 128;
  int wrow0 = r0 + w*32;           // group A rows [wrow0,wrow0+16), B [+16,+32)
  int nt = 4*rblk + 4;
  int jt0 = (s*nt) >> logS, jt1 = ((s+1)*nt) >> logS;
  int grA = wrow0 + lr;
  int grB = wrow0 + 16 + lr;
  int diagA = (wrow0 + 15) >> 5;
  int diagB = (wrow0 + 31) >> 5;

  long qfA[8], qfB[8];
  {
    const unsigned char* qa = q8 + ((size_t)b*T + grA)*D + lc*8;
    const unsigned char* qb = q8 + ((size_t)b*T + grB)*D + lc*8;
    #pragma unroll
    for(int kc=0;kc<8;kc++){
      qfA[kc] = *(const long*)(qa + kc*32);
      qfB[kc] = *(const long*)(qb + kc*32);
    }
  }
  f32x4 oA[16], oB[16];
  #pragma unroll
  for(int n=0;n<16;n++){ oA[n] = (f32x4){0.f,0.f,0.f,0.f}; oB[n] = (f32x4){0.f,0.f,0.f,0.f}; }
  float mA = -INFINITY, lsA = 0.f, mB = -INFINITY, lsB = 0.f;

  const unsigned char*  ktb = k8   + (size_t)b*128*KTB;
  const unsigned short* vtb = vt_g + (size_t)b*128*VT;

  if(jt1 > jt0){
    const unsigned char*  ks = ktb + (size_t)jt0*KTB;
    const unsigned short* vs = vtb + (size_t)jt0*VT;
    for(int c=w; c<28; c+=4){
      if(c < 8) gl_lds16(ks + c*1024 + l*16, (char*)kbuf8[jt0&1] + c*1024);
      else      gl_lds16(vs + (c-8)*512 + l*8, (char*)vbuf[jt0&1] + (c-8)*1024);
    }
  }

  for(int jt=jt0; jt<jt1; jt++){
    int cur = jt & 1;
    asm volatile("s_waitcnt vmcnt(0)" ::: "memory");
    __builtin_amdgcn_s_barrier();
    __builtin_amdgcn_sched_barrier(0);
    if(jt+1 < jt1){
      const unsigned char*  ks = ktb + (size_t)(jt+1)*KTB;
      const unsigned short* vs = vtb + (size_t)(jt+1)*VT;
      for(int c=w; c<28; c+=4){
        if(c < 8) gl_lds16(ks + c*1024 + l*16, (char*)kbuf8[cur^1] + c*1024);
        else      gl_lds16(vs + (c-8)*512 + l*8, (char*)vbuf[cur^1] + (c-8)*1024);
      }
    }
    int j0 = jt*32;
    bool actA = (j0 <= wrow0 + 15);
    bool actB = (j0 <= wrow0 + 31);
    if(actB){
      const unsigned char* kb = kbuf8[cur];
      unsigned soff = ((unsigned)(lr & 7)) << 3;   // row swizzle (same for lr and 16+lr)
      f32x4 sA0={0,0,0,0}, sA1={0,0,0,0}, sB0={0,0,0,0}, sB1={0,0,0,0};
      if(actA){
        #pragma unroll
        for(int kc=0;kc<8;kc++){
          unsigned off = ((unsigned)((kc*4 + lc)*8)) ^ soff;
          long k0 = *(const long*)&kb[(unsigned)lr*256 + off];
          long k1 = *(const long*)&kb[(unsigned)(16 + lr)*256 + off];
          sA0 = __builtin_amdgcn_mfma_f32_16x16x32_fp8_fp8(k0, qfA[kc], sA0, 0,0,0);
          sA1 = __builtin_amdgcn_mfma_f32_16x16x32_fp8_fp8(k1, qfA[kc], sA1, 0,0,0);
          sB0 = __builtin_amdgcn_mfma_f32_16x16x32_fp8_fp8(k0, qfB[kc], sB0, 0,0,0);
          sB1 = __builtin_amdgcn_mfma_f32_16x16x32_fp8_fp8(k1, qfB[kc], sB1, 0,0,0);
        }
      } else {
        #pragma unroll
        for(int kc=0;kc<8;kc++){
          unsigned off = ((unsigned)((kc*4 + lc)*8)) ^ soff;
          long k0 = *(const long*)&kb[(unsigned)lr*256 + off];
          long k1 = *(const long*)&kb[(unsigned)(16 + lr)*256 + off];
          sB0 = __builtin_amdgcn_mfma_f32_16x16x32_fp8_fp8(k0, qfB[kc], sB0, 0,0,0);
          sB1 = __builtin_amdgcn_mfma_f32_16x16x32_fp8_fp8(k1, qfB[kc], sB1, 0,0,0);
        }
      }
      bf16x8 paA, paB;
      // ---- softmax group A (exp2 domain; QSCALE on scores) ----
      if(actA){
        float sv0[4], sv1[4];
        if(jt == diagA){
          #pragma unroll
          for(int r=0;r<4;r++){
            float x0 = sA0[r]*QSCALE; int gj0 = j0 + lc*4 + r;
            float x1 = sA1[r]*QSCALE; int gj1 = gj0 + 16;
            sv0[r] = (gj0 > grA || x0 == 0.0f) ? -INFINITY : x0;
            sv1[r] = (gj1 > grA || x1 == 0.0f) ? -INFINITY : x1;
          }
        } else {
          #pragma unroll
          for(int r=0;r<4;r++){
            float x0 = sA0[r]*QSCALE;
            float x1 = sA1[r]*QSCALE;
            sv0[r] = (x0 == 0.0f) ? -INFINITY : x0;
            sv1[r] = (x1 == 0.0f) ? -INFINITY : x1;
          }
        }
        float pmax = fmaxf(fmaxf(fmaxf(sv0[0],sv0[1]),fmaxf(sv0[2],sv0[3])),
                           fmaxf(fmaxf(sv1[0],sv1[1]),fmaxf(sv1[2],sv1[3])));
        pmax = fmaxf(pmax, __shfl_xor(pmax, 16));
        pmax = fmaxf(pmax, __shfl_xor(pmax, 32));
        bool mv = (pmax > mA + 11.5f);     // defer-max (log2 domain)
        float mn = mv ? pmax : mA;
        float alpha = mv ? exp2f(mA - mn) : 1.0f;
        float p0[4], p1[4];
        #pragma unroll
        for(int r=0;r<4;r++){
          p0[r] = exp2f(sv0[r] - mn);
          p1[r] = exp2f(sv1[r] - mn);
        }
        if(__builtin_amdgcn_ballot_w64(mv)){
          float a0 = __shfl(alpha, lc*4 + 0);
          float a1 = __shfl(alpha, lc*4 + 1);
          float a2 = __shfl(alpha, lc*4 + 2);
          float a3 = __shfl(alpha, lc*4 + 3);
          #pragma unroll
          for(int n=0;n<16;n++){
            oA[n][0] *= a0; oA[n][1] *= a1; oA[n][2] *= a2; oA[n][3] *= a3;
          }
        }
        float ps = ((p0[0]+p0[1])+(p0[2]+p0[3])) + ((p1[0]+p1[1])+(p1[2]+p1[3]));
        lsA = lsA*alpha + ps;
        mA = mn;
        union { unsigned int u[4]; bf16x8 h; } pu;
        pu.u[0] = cvtpk(p0[0], p0[1]); pu.u[1] = cvtpk(p0[2], p0[3]);
        pu.u[2] = cvtpk(p1[0], p1[1]); pu.u[3] = cvtpk(p1[2], p1[3]);
        paA = pu.h;
      }
      // ---- softmax group B ----
      {
        float sv0[4], sv1[4];
        if(jt == diagB){
          #pragma unroll
          for(int r=0;r<4;r++){
            float x0 = sB0[r]*QSCALE; int gj0 = j0 + lc*4 + r;
            float x1 = sB1[r]*QSCALE; int gj1 = gj0 + 16;
            sv0[r] = (gj0 > grB || x0 == 0.0f) ? -INFINITY : x0;
            sv1[r] = (gj1 > grB || x1 == 0.0f) ? -INFINITY : x1;
          }
        } else {
          #pragma unroll
          for(int r=0;r<4;r++){
            float x0 = sB0[r]*QSCALE;
            float x1 = sB1[r]*QSCALE;
            sv0[r] = (x0 == 0.0f) ? -INFINITY : x0;
            sv1[r] = (x1 == 0.0f) ? -INFINITY : x1;
          }
        }
        float pmax = fmaxf(fmaxf(fmaxf(sv0[0],sv0[1]),fmaxf(sv0[2],sv0[3])),
                           fmaxf(fmaxf(sv1[0],sv1[1]),fmaxf(sv1[2],sv1[3])));
        pmax = fmaxf(pmax, __shfl_xor(pmax, 16));
        pmax = fmaxf(pmax, __shfl_xor(pmax, 32));
        bool mv = (pmax > mB + 11.5f);
        float mn = mv ? pmax : mB;
        float alpha = mv ? exp2f(mB - mn) : 1.0f;
        float p0[4], p1[4];
        #pragma unroll
        for(int r=0;r<4;r++){
          p0[r] = exp2f(sv0[r] - mn);
          p1[r] = exp2f(sv1[r] - mn);
        }
        if(__builtin_amdgcn_ballot_w64(mv)){
          float a0 = __shfl(alpha, lc*4 + 0);
          float a1 = __shfl(alpha, lc*4 + 1);
          float a2 = __shfl(alpha, lc*4 + 2);
          float a3 = __shfl(alpha, lc*4 + 3);
          #pragma unroll
          for(int n=0;n<16;n++){
            oB[n][0] *= a0; oB[n][1] *= a1; oB[n][2] *= a2; oB[n][3] *= a3;
          }
        }
        float ps = ((p0[0]+p0[1])+(p0[2]+p0[3])) + ((p1[0]+p1[1])+(p1[2]+p1[3]));
        lsB = lsB*alpha + ps;
        mB = mn;
        union { unsigned int u[4]; bf16x8 h; } pu;
        pu.u[0] = cvtpk(p0[0], p0[1]); pu.u[1] = cvtpk(p0[2], p0[3]);
        pu.u[2] = cvtpk(p1[0], p1[1]); pu.u[3] = cvtpk(p1[2], p1[3]);
        paB = pu.h;
      }
      // ---- PV (bf16, unchanged): each V fragment read once, both groups ----
      if(actA){
        #pragma unroll
        for(int n=0;n<16;n++){
          bf16x8 vf = *(const bf16x8*)&vbuf[cur][(n*16 + lr)*40 + lc*8];
          oA[n] = __builtin_amdgcn_mfma_f32_16x16x32_bf16(paA, vf, oA[n], 0,0,0);
          oB[n] = __builtin_amdgcn_mfma_f32_16x16x32_bf16(paB, vf, oB[n], 0,0,0);
        }
      } else {
        #pragma unroll
        for(int n=0;n<16;n++){
          bf16x8 vf = *(const bf16x8*)&vbuf[cur][(n*16 + lr)*40 + lc*8];
          oB[n] = __builtin_amdgcn_mfma_f32_16x16x32_bf16(paB, vf, oB[n], 0,0,0);
        }
      }
    }
  }

  // epilogue: permuted bf16 partial via cvt_pk + b128 stores; (m, l) in log2 domain
  unsigned short* obase = parts + (size_t)s*PSTR + ((size_t)b*T + wrow0)*D;
  #pragma unroll
  for(int r=0;r<4;r++){
    int row = lc*4 + r;
    unsigned int wa[8], wb[8];
    #pragma unroll
    for(int k=0;k<8;k++){
      wa[k] = cvtpk(oA[2*k][r], oA[2*k+1][r]);
      wb[k] = cvtpk(oB[2*k][r], oB[2*k+1][r]);
    }
    *(u32x4*)&obase[(size_t)row*D + lr*16]          = (u32x4){wa[0],wa[1],wa[2],wa[3]};
    *(u32x4*)&obase[(size_t)row*D + lr*16 + 8]      = (u32x4){wa[4],wa[5],wa[6],wa[7]};
    *(u32x4*)&obase[(size_t)(row+16)*D + lr*16]     = (u32x4){wb[0],wb[1],wb[2],wb[3]};
    *(u32x4*)&obase[(size_t)(row+16)*D + lr*16 + 8] = (u32x4){wb[4],wb[5],wb[6],wb[7]};
  }
  lsA += __shfl_xor(lsA, 16); lsA += __shfl_xor(lsA, 32);
  lsB += __shfl_xor(lsB, 16); lsB += __shfl_xor(lsB, 32);
  if(l < 16){
    float* mlbA = ml + ((size_t)s*4*T + (size_t)b*T + wrow0 + lr)*2;
    mlbA[0] = mA; mlbA[1] = lsA;
    float* mlbB = ml + ((size_t)s*4*T + (size_t)b*T + wrow0 + 16 + lr)*2;
    mlbB[0] = mB; mlbB[1] = lsB;
  }
}

// ---------------- combine: thread = (row, lr); un-permutes parts; exp2 domain ----------------
__global__ __launch_bounds__(256) void combine_kernel(
    const unsigned short* __restrict__ parts, const float* __restrict__ ml,
    float* __restrict__ out, int S){
  int t = blockIdx.x*256 + threadIdx.x;   // [0, 4*T*16)
  int row = t >> 4;                       // b*T + row
  int lr  = t & 15;
  float msv[8], lsv[8];
  float mm = -INFINITY;
  #pragma unroll
  for(int s=0;s<8;s++){
    if(s >= S) break;
    msv[s] = ml[((size_t)s*4*T + row)*2];
    lsv[s] = ml[((size_t)s*4*T + row)*2 + 1];
    mm = fmaxf(mm, msv[s]);
  }
  float denom = 0.f;
  float acc[16];
  #pragma unroll
  for(int n=0;n<16;n++) acc[n] = 0.f;
  #pragma unroll
  for(int s=0;s<8;s++){
    if(s >= S) break;
    float as = exp2f(msv[s] - mm);
    if(as != 0.0f){
      denom += as*lsv[s];
      const unsigned short* src = parts + (size_t)s*PSTR + (size_t)row*D + lr*16;
      u16x8 v0 = *(const u16x8*)src;
      u16x8 v1 = *(const u16x8*)(src + 8);
      #pragma unroll
      for(int n=0;n<8;n++){ acc[n] += as*bf2f(v0[n]); acc[8+n] += as*bf2f(v1[n]); }
    }
  }
  float inv = 1.0f/denom;
  float* orow = out + (size_t)row*D;
  #pragma unroll
  for(int n=0;n<16;n++) orow[n*16 + lr] = acc[n]*inv;   // d = n*16+lr (un-permute)
}

extern "C" void kernel_launch(void* const* d_in, const int* in_sizes, int n_in,
                              void* d_out, int out_size, void* d_ws, size_t ws_size,
                              hipStream_t stream){
  (void)in_sizes; (void)n_in; (void)out_size;
  const float* query = (const float*)d_in[0];
  const float* value = (const float*)d_in[1];
  const float* q_vec = (const float*)d_in[2];
  const float* k_vec = (const float*)d_in[3];
  const float* v_vec = (const float*)d_in[4];
  const float* Wq    = (const float*)d_in[5];
  const float* bq    = (const float*)d_in[6];
  const float* Ws    = (const float*)d_in[7];
  const float* bs    = (const float*)d_in[8];
  const float* Wt    = (const float*)d_in[9];
  const float* bt    = (const float*)d_in[10];
  char* ws = (char*)d_ws;
  unsigned char*  q8   = (unsigned char*)(ws);              // 4,194,304 B (in old 8MB slot)
  unsigned char*  k8   = (unsigned char*)(ws + 8388608);    // 4,194,304 B (in old slot)
  unsigned short* vt_g = (unsigned short*)(ws + 17301504);  // 10,485,760 B
  unsigned short* wq_g = (unsigned short*)(ws + 27787264);  //    163,840 B
  float* gates         = (float*)(ws + 27951104);           //      4,096 B
  unsigned short* parts= (unsigned short*)(ws + 27955200);  // S*8,388,608 B
  float* out = (float*)d_out;

  size_t base = 27955200;
  size_t mlsz = (size_t)8*4*T*2*4;
  int logS;
  if(ws_size >= base + 8*PSTR*2 + mlsz)      logS = 3;
  else if(ws_size >= base + 4*PSTR*2 + mlsz) logS = 2;
  else                                       logS = 1;
  int S = 1 << logS;
  float* ml = (float*)(ws + base + (size_t)S*PSTR*2);

  hipLaunchKernelGGL(prep_kernel, dim3(9),   dim3(256), 0, stream,
                     q_vec, k_vec, v_vec, Ws, bs, Wt, bt, Wq, gates, wq_g);
  hipLaunchKernelGGL(mid_kernel,  dim3(768), dim3(256), 0, stream,
                     query, wq_g, bq, gates, q8, value, k8, vt_g);
  hipLaunchKernelGGL(flash_kernel, dim3(128*S), dim3(256), 0, stream,
                     q8, k8, vt_g, parts, ml, logS);
  hipLaunchKernelGGL(combine_kernel, dim3((4*T*16)/256), dim3(256), 0, stream,
                     parts, ml, out, S);
}

// Round 17
// 109.976 us; speedup vs baseline: 4.5346x; 1.0174x over previous
//
#include <hip/hip_runtime.h>
#include <math.h>

#define D 256
#define T 4096
#define KTB 8192           // BYTES per fp8 K tile (32 rows x 256B, swizzled)
#define VT (20480/2)       // shorts per V^T tile
#define PSTR ((size_t)4*T*D)  // shorts per bf16 partial buffer

typedef __attribute__((ext_vector_type(8))) short bf16x8;
typedef __attribute__((ext_vector_type(4))) float f32x4;
typedef __attribute__((ext_vector_type(8))) unsigned short u16x8;
typedef __attribute__((ext_vector_type(4))) unsigned int u32x4;

// log2(e)/16: softmax 1/sqrt(D) scale AND exp->exp2 conversion (applied to scores)
#define QSCALE 0.0901684850f

__device__ __forceinline__ unsigned short f2bf(float x){
  unsigned int u = __float_as_uint(x);
  unsigned int r = (u + 0x7FFFu + ((u >> 16) & 1u)) >> 16;
  return (unsigned short)r;
}
__device__ __forceinline__ float bf2f(unsigned short h){
  return __uint_as_float(((unsigned int)h) << 16);
}
__device__ __forceinline__ unsigned int cvtpk(float lo, float hi){
  unsigned int w;
  asm("v_cvt_pk_bf16_f32 %0, %1, %2" : "=v"(w) : "v"(lo), "v"(hi));
  return w;
}
// 2x f32 -> 2x fp8 e4m3 in bits [15:0]
__device__ __forceinline__ unsigned int cvtpk8(float lo, float hi){
  unsigned int w;
  asm("v_cvt_pk_fp8_f32 %0, %1, %2" : "=v"(w) : "v"(lo), "v"(hi));
  return w;
}

__device__ __forceinline__ void gl_lds16(const void* g, void* l){
  __builtin_amdgcn_global_load_lds((const __attribute__((address_space(1))) unsigned int*)g,
                                   (__attribute__((address_space(3))) unsigned int*)l, 16, 0, 0);
}

// ---------------- prep: gates (block 0) + Wq bf16 image (blocks 1..8) ----------------
__global__ __launch_bounds__(256) void prep_kernel(
    const float* __restrict__ q_vec, const float* __restrict__ k_vec,
    const float* __restrict__ v_vec, const float* __restrict__ Ws,
    const float* __restrict__ bs, const float* __restrict__ Wt,
    const float* __restrict__ bt, const float* __restrict__ Wq,
    float* __restrict__ gates, unsigned short* __restrict__ wq_g){
  int t = threadIdx.x;
  if(blockIdx.x == 0){
    __shared__ float vv[D];
    vv[t]         = 1.f/(1.f + __expf(-v_vec[t]));
    gates[t]      = 1.f/(1.f + __expf(-q_vec[t]));   // gq
    gates[D + t]  = 1.f/(1.f + __expf(-k_vec[t]));   // gk
    __syncthreads();
    const f32x4* wsr = (const f32x4*)(Ws + (size_t)t*D);
    const f32x4* wtr = (const f32x4*)(Wt + (size_t)t*D);
    const f32x4* vvv = (const f32x4*)vv;
    f32x4 a0 = {0,0,0,0}, a1 = {0,0,0,0}, c0 = {0,0,0,0}, c1 = {0,0,0,0};
    for(int i=0;i<64;i+=2){
      f32x4 v0 = vvv[i], v1 = vvv[i+1];
      a0 += wsr[i]*v0; a1 += wsr[i+1]*v1;
      c0 += wtr[i]*v0; c1 += wtr[i+1]*v1;
    }
    f32x4 as = a0 + a1, cs = c0 + c1;
    float s1 = bs[t] + as[0]+as[1]+as[2]+as[3];
    float s2 = bt[t] + cs[0]+cs[1]+cs[2]+cs[3];
    gates[2*D + t] = (1.f/(1.f + __expf(-s1))) * tanhf(s2);  // v_gate
  } else {
    int kc = blockIdx.x - 1;
    const float* src = Wq + (size_t)t*D + kc*32;
    unsigned short* dst = wq_g + (size_t)kc*10240 + t*40;
    #pragma unroll
    for(int u=0;u<4;u++){
      bf16x8 pk;
      #pragma unroll
      for(int x=0;x<8;x++) pk[x] = (short)f2bf(src[u*8+x]);
      *(bf16x8*)&dst[u*8] = pk;
    }
  }
}

// ---------------- mid: proj (blocks 0..255) + prep1 (blocks 256..767) ----------------
__global__ __launch_bounds__(256) void mid_kernel(
    const float* __restrict__ query, const unsigned short* __restrict__ wq_g,
    const float* __restrict__ bq, const float* __restrict__ gates,
    unsigned char* __restrict__ q8,
    const float* __restrict__ value,
    unsigned char* __restrict__ k8, unsigned short* __restrict__ vt_g){
  __shared__ __align__(16) unsigned short smem[2][10240];
  int tid = threadIdx.x;
  if(blockIdx.x < 256){
    // ---- proj: q = (query @ Wq^T + bq) * gq, fp8 out ----
    int w = tid >> 6; int l = tid & 63;
    int lr = l & 15, lc = l >> 4;
    int r0 = blockIdx.x * 64;
    f32x4 acc[16];
    #pragma unroll
    for(int n=0;n<16;n++) acc[n] = (f32x4){0.f,0.f,0.f,0.f};
    const float* qrow = query + (size_t)(r0 + w*16 + lr)*D;
    #pragma unroll
    for(int i=0;i<5;i++){ int c = i*256 + tid; gl_lds16(wq_g + c*8, (char*)smem[0] + c*16); }
    __syncthreads();
    int cur = 0;
    for(int kc=0; kc<8; kc++){
      if(kc < 7){
        #pragma unroll
        for(int i=0;i<5;i++){ int c = i*256 + tid;
          gl_lds16(wq_g + (size_t)(kc+1)*10240 + c*8, (char*)smem[cur^1] + c*16); }
      }
      bf16x8 af;
      {
        const float* s = qrow + kc*32 + lc*8;
        #pragma unroll
        for(int x=0;x<8;x++) af[x] = (short)f2bf(s[x]);
      }
      #pragma unroll
      for(int n=0;n<16;n++){
        bf16x8 bfrag = *(const bf16x8*)&smem[cur][(n*16 + lr)*40 + lc*8];
        acc[n] = __builtin_amdgcn_mfma_f32_16x16x32_bf16(af, bfrag, acc[n], 0, 0, 0);
      }
      __syncthreads();
      cur ^= 1;
    }
    #pragma unroll
    for(int n=0;n<16;n++){
      int col = n*16 + lr;
      float bb = bq[col], gg = gates[col];
      float v0 = (acc[n][0] + bb) * gg;
      float v1 = (acc[n][1] + bb) * gg;
      float v2 = (acc[n][2] + bb) * gg;
      float v3 = (acc[n][3] + bb) * gg;
      unsigned int wlo = cvtpk8(v0, v1);
      unsigned int whi = cvtpk8(v2, v3);
      int row0 = r0 + w*16 + lc*4;
      q8[(size_t)(row0+0)*D + col] = (unsigned char)(wlo);
      q8[(size_t)(row0+1)*D + col] = (unsigned char)(wlo >> 8);
      q8[(size_t)(row0+2)*D + col] = (unsigned char)(whi);
      q8[(size_t)(row0+3)*D + col] = (unsigned char)(whi >> 8);
    }
  } else {
    // ---- prep1: K fp8 (swizzled 256B rows) and V^T bf16 (k-permuted) ----
    int bid2 = blockIdx.x - 256;
    int b = bid2 >> 7, jt = bid2 & 127;
    const float* vbase = value + ((size_t)b*T + jt*32)*D;
    const float* gk = gates + D;
    const float* vg = gates + 2*D;
    unsigned char* kt = k8 + (size_t)bid2 * KTB;
    unsigned short* vt = vt_g + (size_t)bid2 * VT;
    #pragma unroll
    for(int i=0;i<4;i++){
      int g = i*256 + tid; int j = g >> 5, c = g & 31;
      const float* src = vbase + j*D + c*8;
      float f[8];
      #pragma unroll
      for(int x=0;x<8;x++) f[x] = src[x] * gk[c*8+x];
      unsigned int a0 = cvtpk8(f[0], f[1]);
      unsigned int a1 = cvtpk8(f[2], f[3]);
      unsigned int a2 = cvtpk8(f[4], f[5]);
      unsigned int a3 = cvtpk8(f[6], f[7]);
      unsigned long lo = (unsigned long)((a0 & 0xffffu) | (a1 << 16));
      unsigned long hi = (unsigned long)((a2 & 0xffffu) | (a3 << 16));
      unsigned int off = (unsigned)(c*8) ^ (unsigned)((j & 7) << 3);
      *(unsigned long*)&kt[(size_t)j*256 + off] = lo | (hi << 32);
    }
    float* lds = (float*)smem;   // [32][68]
    for(int c=0;c<4;c++){
      __syncthreads();
      {
        int row = tid >> 3, cg = tid & 7;
        const float* src = vbase + (size_t)row*D + c*64 + cg*8;
        f32x4 v0 = *(const f32x4*)src;
        f32x4 v1 = *(const f32x4*)(src + 4);
        *(f32x4*)&lds[row*68 + cg*8]     = v0;
        *(f32x4*)&lds[row*68 + cg*8 + 4] = v1;
      }
      __syncthreads();
      {
        int d0l = tid >> 2, u = tid & 3;
        int d0 = c*64 + d0l;
        float gd = vg[d0];
        bf16x8 pk;
        #pragma unroll
        for(int x=0;x<8;x++){
          int p = u*8 + x;
          int ksrc = ((p>>3)<<2) + (p&3) + (((p>>2)&1)<<4);  // PV A-frag k-perm
          pk[x] = (short)f2bf(lds[ksrc*68 + d0l] * gd);
        }
        *(bf16x8*)&vt[d0*40 + u*8] = pk;
      }
    }
  }
}

// ---------------- flash: fp8 QK^T, bf16 PV; T4 split counted-waits ----------------
// Per-wave stage issue order: 2 K chunks then 5 V chunks (7 loads/stage).
// Top of tile: vmcnt(5)+barrier => all waves' K(jt) landed; QK runs while V flies.
// Before PV: vmcnt(2)+barrier => all waves' V(jt) landed (2 K(jt+1) stay in flight).
__global__ __launch_bounds__(256, 2) void flash_kernel(
    const unsigned char* __restrict__ q8,
    const unsigned char* __restrict__ k8,
    const unsigned short* __restrict__ vt_g,
    unsigned short* __restrict__ parts,
    float* __restrict__ ml, int logS){
  __shared__ __align__(16) unsigned char kbuf8[2][KTB];
  __shared__ __align__(16) unsigned short vbuf[2][VT];
  int tid = threadIdx.x; int w = tid >> 6, l = tid & 63;
  int lr = l & 15, lc = l >> 4;
  int S = 1 << logS;
  int bid = blockIdx.x;
  int x = bid & 7; int b = x >> 1; int p = x & 1;   // XCD lane = (b, jt-half p)
  int item = bid >> 3;                              // heavy rblk first
  int half = S >> 1;
  int rblk = 31 - (item / half);
  int s = p*half + (item % half);
  int r0 = rblk * 128;
  int wrow0 = r0 + w*32;           // group A rows [wrow0,wrow0+16), B [+16,+32)
  int nt = 4*rblk + 4;
  int jt0 = (s*nt) >> logS, jt1 = ((s+1)*nt) >> logS;
  int grA = wrow0 + lr;
  int grB = wrow0 + 16 + lr;
  int diagA = (wrow0 + 15) >> 5;
  int diagB = (wrow0 + 31) >> 5;

  long qfA[8], qfB[8];
  {
    const unsigned char* qa = q8 + ((size_t)b*T + grA)*D + lc*8;
    const unsigned char* qb = q8 + ((size_t)b*T + grB)*D + lc*8;
    #pragma unroll
    for(int kc=0;kc<8;kc++){
      qfA[kc] = *(const long*)(qa + kc*32);
      qfB[kc] = *(const long*)(qb + kc*32);
    }
  }
  f32x4 oA[16], oB[16];
  #pragma unroll
  for(int n=0;n<16;n++){ oA[n] = (f32x4){0.f,0.f,0.f,0.f}; oB[n] = (f32x4){0.f,0.f,0.f,0.f}; }
  float mA = -INFINITY, lsA = 0.f, mB = -INFINITY, lsB = 0.f;

  const unsigned char*  ktb = k8   + (size_t)b*128*KTB;
  const unsigned short* vtb = vt_g + (size_t)b*128*VT;

  if(jt1 > jt0){
    const unsigned char*  ks = ktb + (size_t)jt0*KTB;
    const unsigned short* vs = vtb + (size_t)jt0*VT;
    for(int c=w; c<8; c+=4)    gl_lds16(ks + c*1024 + l*16, (char*)kbuf8[jt0&1] + c*1024);
    for(int c=8+w; c<28; c+=4) gl_lds16(vs + (c-8)*512 + l*8, (char*)vbuf[jt0&1] + (c-8)*1024);
  }

  for(int jt=jt0; jt<jt1; jt++){
    int cur = jt & 1;
    // wave's 2 K(jt) chunks are the oldest of 7 outstanding -> vmcnt(5) = K landed
    asm volatile("s_waitcnt vmcnt(5)" ::: "memory");
    __builtin_amdgcn_s_barrier();      // all waves' K(jt) landed; compute(jt-1) done
    __builtin_amdgcn_sched_barrier(0);
    bool hasnext = (jt+1 < jt1);
    if(hasnext){
      const unsigned char* ks = ktb + (size_t)(jt+1)*KTB;
      for(int c=w; c<8; c+=4) gl_lds16(ks + c*1024 + l*16, (char*)kbuf8[cur^1] + c*1024);
    }
    int j0 = jt*32;
    bool actA = (j0 <= wrow0 + 15);
    bool actB = (j0 <= wrow0 + 31);
    bf16x8 paA, paB;
    if(actB){
      const unsigned char* kb = kbuf8[cur];
      unsigned soff = ((unsigned)(lr & 7)) << 3;
      f32x4 sA0={0,0,0,0}, sA1={0,0,0,0}, sB0={0,0,0,0}, sB1={0,0,0,0};
      if(actA){
        #pragma unroll
        for(int kc=0;kc<8;kc++){
          unsigned off = ((unsigned)((kc*4 + lc)*8)) ^ soff;
          long k0 = *(const long*)&kb[(unsigned)lr*256 + off];
          long k1 = *(const long*)&kb[(unsigned)(16 + lr)*256 + off];
          sA0 = __builtin_amdgcn_mfma_f32_16x16x32_fp8_fp8(k0, qfA[kc], sA0, 0,0,0);
          sA1 = __builtin_amdgcn_mfma_f32_16x16x32_fp8_fp8(k1, qfA[kc], sA1, 0,0,0);
          sB0 = __builtin_amdgcn_mfma_f32_16x16x32_fp8_fp8(k0, qfB[kc], sB0, 0,0,0);
          sB1 = __builtin_amdgcn_mfma_f32_16x16x32_fp8_fp8(k1, qfB[kc], sB1, 0,0,0);
        }
      } else {
        #pragma unroll
        for(int kc=0;kc<8;kc++){
          unsigned off = ((unsigned)((kc*4 + lc)*8)) ^ soff;
          long k0 = *(const long*)&kb[(unsigned)lr*256 + off];
          long k1 = *(const long*)&kb[(unsigned)(16 + lr)*256 + off];
          sB0 = __builtin_amdgcn_mfma_f32_16x16x32_fp8_fp8(k0, qfB[kc], sB0, 0,0,0);
          sB1 = __builtin_amdgcn_mfma_f32_16x16x32_fp8_fp8(k1, qfB[kc], sB1, 0,0,0);
        }
      }
      // ---- softmax group A (exp2 domain; QSCALE on scores) ----
      if(actA){
        float sv0[4], sv1[4];
        if(jt == diagA){
          #pragma unroll
          for(int r=0;r<4;r++){
            float x0 = sA0[r]*QSCALE; int gj0 = j0 + lc*4 + r;
            float x1 = sA1[r]*QSCALE; int gj1 = gj0 + 16;
            sv0[r] = (gj0 > grA || x0 == 0.0f) ? -INFINITY : x0;
            sv1[r] = (gj1 > grA || x1 == 0.0f) ? -INFINITY : x1;
          }
        } else {
          #pragma unroll
          for(int r=0;r<4;r++){
            float x0 = sA0[r]*QSCALE;
            float x1 = sA1[r]*QSCALE;
            sv0[r] = (x0 == 0.0f) ? -INFINITY : x0;
            sv1[r] = (x1 == 0.0f) ? -INFINITY : x1;
          }
        }
        float pmax = fmaxf(fmaxf(fmaxf(sv0[0],sv0[1]),fmaxf(sv0[2],sv0[3])),
                           fmaxf(fmaxf(sv1[0],sv1[1]),fmaxf(sv1[2],sv1[3])));
        pmax = fmaxf(pmax, __shfl_xor(pmax, 16));
        pmax = fmaxf(pmax, __shfl_xor(pmax, 32));
        bool mv = (pmax > mA + 11.5f);
        float mn = mv ? pmax : mA;
        float alpha = mv ? exp2f(mA - mn) : 1.0f;
        float p0[4], p1[4];
        #pragma unroll
        for(int r=0;r<4;r++){
          p0[r] = exp2f(sv0[r] - mn);
          p1[r] = exp2f(sv1[r] - mn);
        }
        if(__builtin_amdgcn_ballot_w64(mv)){
          float a0 = __shfl(alpha, lc*4 + 0);
          float a1 = __shfl(alpha, lc*4 + 1);
          float a2 = __shfl(alpha, lc*4 + 2);
          float a3 = __shfl(alpha, lc*4 + 3);
          #pragma unroll
          for(int n=0;n<16;n++){
            oA[n][0] *= a0; oA[n][1] *= a1; oA[n][2] *= a2; oA[n][3] *= a3;
          }
        }
        float ps = ((p0[0]+p0[1])+(p0[2]+p0[3])) + ((p1[0]+p1[1])+(p1[2]+p1[3]));
        lsA = lsA*alpha + ps;
        mA = mn;
        union { unsigned int u[4]; bf16x8 h; } pu;
        pu.u[0] = cvtpk(p0[0], p0[1]); pu.u[1] = cvtpk(p0[2], p0[3]);
        pu.u[2] = cvtpk(p1[0], p1[1]); pu.u[3] = cvtpk(p1[2], p1[3]);
        paA = pu.h;
      }
      // ---- softmax group B ----
      {
        float sv0[4], sv1[4];
        if(jt == diagB){
          #pragma unroll
          for(int r=0;r<4;r++){
            float x0 = sB0[r]*QSCALE; int gj0 = j0 + lc*4 + r;
            float x1 = sB1[r]*QSCALE; int gj1 = gj0 + 16;
            sv0[r] = (gj0 > grB || x0 == 0.0f) ? -INFINITY : x0;
            sv1[r] = (gj1 > grB || x1 == 0.0f) ? -INFINITY : x1;
          }
        } else {
          #pragma unroll
          for(int r=0;r<4;r++){
            float x0 = sB0[r]*QSCALE;
            float x1 = sB1[r]*QSCALE;
            sv0[r] = (x0 == 0.0f) ? -INFINITY : x0;
            sv1[r] = (x1 == 0.0f) ? -INFINITY : x1;
          }
        }
        float pmax = fmaxf(fmaxf(fmaxf(sv0[0],sv0[1]),fmaxf(sv0[2],sv0[3])),
                           fmaxf(fmaxf(sv1[0],sv1[1]),fmaxf(sv1[2],sv1[3])));
        pmax = fmaxf(pmax, __shfl_xor(pmax, 16));
        pmax = fmaxf(pmax, __shfl_xor(pmax, 32));
        bool mv = (pmax > mB + 11.5f);
        float mn = mv ? pmax : mB;
        float alpha = mv ? exp2f(mB - mn) : 1.0f;
        float p0[4], p1[4];
        #pragma unroll
        for(int r=0;r<4;r++){
          p0[r] = exp2f(sv0[r] - mn);
          p1[r] = exp2f(sv1[r] - mn);
        }
        if(__builtin_amdgcn_ballot_w64(mv)){
          float a0 = __shfl(alpha, lc*4 + 0);
          float a1 = __shfl(alpha, lc*4 + 1);
          float a2 = __shfl(alpha, lc*4 + 2);
          float a3 = __shfl(alpha, lc*4 + 3);
          #pragma unroll
          for(int n=0;n<16;n++){
            oB[n][0] *= a0; oB[n][1] *= a1; oB[n][2] *= a2; oB[n][3] *= a3;
          }
        }
        float ps = ((p0[0]+p0[1])+(p0[2]+p0[3])) + ((p1[0]+p1[1])+(p1[2]+p1[3]));
        lsB = lsB*alpha + ps;
        mB = mn;
        union { unsigned int u[4]; bf16x8 h; } pu;
        pu.u[0] = cvtpk(p0[0], p0[1]); pu.u[1] = cvtpk(p0[2], p0[3]);
        pu.u[2] = cvtpk(p1[0], p1[1]); pu.u[3] = cvtpk(p1[2], p1[3]);
        paB = pu.h;
      }
    }
    // V(jt) wait: oldest 5 of 7 outstanding are V(jt) (2 K(jt+1) stay in flight)
    if(hasnext){
      asm volatile("s_waitcnt vmcnt(2)" ::: "memory");
    } else {
      asm volatile("s_waitcnt vmcnt(0)" ::: "memory");
    }
    __builtin_amdgcn_s_barrier();      // all waves' V(jt) landed
    __builtin_amdgcn_sched_barrier(0);
    if(hasnext){
      const unsigned short* vs = vtb + (size_t)(jt+1)*VT;
      for(int c=8+w; c<28; c+=4) gl_lds16(vs + (c-8)*512 + l*8, (char*)vbuf[cur^1] + (c-8)*1024);
    }
    // ---- PV (bf16): each V fragment read once, both groups ----
    if(actB){
      if(actA){
        #pragma unroll
        for(int n=0;n<16;n++){
          bf16x8 vf = *(const bf16x8*)&vbuf[cur][(n*16 + lr)*40 + lc*8];
          oA[n] = __builtin_amdgcn_mfma_f32_16x16x32_bf16(paA, vf, oA[n], 0,0,0);
          oB[n] = __builtin_amdgcn_mfma_f32_16x16x32_bf16(paB, vf, oB[n], 0,0,0);
        }
      } else {
        #pragma unroll
        for(int n=0;n<16;n++){
          bf16x8 vf = *(const bf16x8*)&vbuf[cur][(n*16 + lr)*40 + lc*8];
          oB[n] = __builtin_amdgcn_mfma_f32_16x16x32_bf16(paB, vf, oB[n], 0,0,0);
        }
      }
    }
  }

  // epilogue: permuted bf16 partial via cvt_pk + b128 stores; (m, l) in log2 domain
  unsigned short* obase = parts + (size_t)s*PSTR + ((size_t)b*T + wrow0)*D;
  #pragma unroll
  for(int r=0;r<4;r++){
    int row = lc*4 + r;
    unsigned int wa[8], wb[8];
    #pragma unroll
    for(int k=0;k<8;k++){
      wa[k] = cvtpk(oA[2*k][r], oA[2*k+1][r]);
      wb[k] = cvtpk(oB[2*k][r], oB[2*k+1][r]);
    }
    *(u32x4*)&obase[(size_t)row*D + lr*16]          = (u32x4){wa[0],wa[1],wa[2],wa[3]};
    *(u32x4*)&obase[(size_t)row*D + lr*16 + 8]      = (u32x4){wa[4],wa[5],wa[6],wa[7]};
    *(u32x4*)&obase[(size_t)(row+16)*D + lr*16]     = (u32x4){wb[0],wb[1],wb[2],wb[3]};
    *(u32x4*)&obase[(size_t)(row+16)*D + lr*16 + 8] = (u32x4){wb[4],wb[5],wb[6],wb[7]};
  }
  lsA += __shfl_xor(lsA, 16); lsA += __shfl_xor(lsA, 32);
  lsB += __shfl_xor(lsB, 16); lsB += __shfl_xor(lsB, 32);
  if(l < 16){
    float* mlbA = ml + ((size_t)s*4*T + (size_t)b*T + wrow0 + lr)*2;
    mlbA[0] = mA; mlbA[1] = lsA;
    float* mlbB = ml + ((size_t)s*4*T + (size_t)b*T + wrow0 + 16 + lr)*2;
    mlbB[0] = mB; mlbB[1] = lsB;
  }
}

// ---------------- combine: thread = (row, lr); un-permutes parts; exp2 domain ----------------
__global__ __launch_bounds__(256) void combine_kernel(
    const unsigned short* __restrict__ parts, const float* __restrict__ ml,
    float* __restrict__ out, int S){
  int t = blockIdx.x*256 + threadIdx.x;   // [0, 4*T*16)
  int row = t >> 4;                       // b*T + row
  int lr  = t & 15;
  float msv[8], lsv[8];
  float mm = -INFINITY;
  #pragma unroll
  for(int s=0;s<8;s++){
    if(s >= S) break;
    msv[s] = ml[((size_t)s*4*T + row)*2];
    lsv[s] = ml[((size_t)s*4*T + row)*2 + 1];
    mm = fmaxf(mm, msv[s]);
  }
  float denom = 0.f;
  float acc[16];
  #pragma unroll
  for(int n=0;n<16;n++) acc[n] = 0.f;
  #pragma unroll
  for(int s=0;s<8;s++){
    if(s >= S) break;
    float as = exp2f(msv[s] - mm);
    if(as != 0.0f){
      denom += as*lsv[s];
      const unsigned short* src = parts + (size_t)s*PSTR + (size_t)row*D + lr*16;
      u16x8 v0 = *(const u16x8*)src;
      u16x8 v1 = *(const u16x8*)(src + 8);
      #pragma unroll
      for(int n=0;n<8;n++){ acc[n] += as*bf2f(v0[n]); acc[8+n] += as*bf2f(v1[n]); }
    }
  }
  float inv = 1.0f/denom;
  float* orow = out + (size_t)row*D;
  #pragma unroll
  for(int n=0;n<16;n++) orow[n*16 + lr] = acc[n]*inv;   // d = n*16+lr (un-permute)
}

extern "C" void kernel_launch(void* const* d_in, const int* in_sizes, int n_in,
                              void* d_out, int out_size, void* d_ws, size_t ws_size,
                              hipStream_t stream){
  (void)in_sizes; (void)n_in; (void)out_size;
  const float* query = (const float*)d_in[0];
  const float* value = (const float*)d_in[1];
  const float* q_vec = (const float*)d_in[2];
  const float* k_vec = (const float*)d_in[3];
  const float* v_vec = (const float*)d_in[4];
  const float* Wq    = (const float*)d_in[5];
  const float* bq    = (const float*)d_in[6];
  const float* Ws    = (const float*)d_in[7];
  const float* bs    = (const float*)d_in[8];
  const float* Wt    = (const float*)d_in[9];
  const float* bt    = (const float*)d_in[10];
  char* ws = (char*)d_ws;
  unsigned char*  q8   = (unsigned char*)(ws);              // 4,194,304 B
  unsigned char*  k8   = (unsigned char*)(ws + 8388608);    // 4,194,304 B
  unsigned short* vt_g = (unsigned short*)(ws + 17301504);  // 10,485,760 B
  unsigned short* wq_g = (unsigned short*)(ws + 27787264);  //    163,840 B
  float* gates         = (float*)(ws + 27951104);           //      4,096 B
  unsigned short* parts= (unsigned short*)(ws + 27955200);  // S*8,388,608 B
  float* out = (float*)d_out;

  size_t base = 27955200;
  size_t mlsz = (size_t)8*4*T*2*4;
  int logS;
  if(ws_size >= base + 8*PSTR*2 + mlsz)      logS = 3;
  else if(ws_size >= base + 4*PSTR*2 + mlsz) logS = 2;
  else                                       logS = 1;
  int S = 1 << logS;
  float* ml = (float*)(ws + base + (size_t)S*PSTR*2);

  hipLaunchKernelGGL(prep_kernel, dim3(9),   dim3(256), 0, stream,
                     q_vec, k_vec, v_vec, Ws, bs, Wt, bt, Wq, gates, wq_g);
  hipLaunchKernelGGL(mid_kernel,  dim3(768), dim3(256), 0, stream,
                     query, wq_g, bq, gates, q8, value, k8, vt_g);
  hipLaunchKernelGGL(flash_kernel, dim3(128*S), dim3(256), 0, stream,
                     q8, k8, vt_g, parts, ml, logS);
  hipLaunchKernelGGL(combine_kernel, dim3((4*T*16)/256), dim3(256), 0, stream,
                     parts, ml, out, S);
}